// Round 1
// baseline (4288.504 us; speedup 1.0000x reference)
//
#include <hip/hip_runtime.h>
#include <math.h>

namespace {

constexpr int Bc = 8, Sc = 1024, Dc = 512, Hc = 8, FFc = 2048, Lc = 4, OUTc = 6;

__device__ __forceinline__ void ld4(float d[4], const float* s) {
    float4 t = *(const float4*)s;
    d[0] = t.x; d[1] = t.y; d[2] = t.z; d[3] = t.w;
}

// ---------------- proj + positional encoding + layernorm ----------------
// one wave per token; lane holds 8 of the 512 features (two float4 groups)
__global__ __launch_bounds__(256) void proj_pe_ln(
    const float* __restrict__ x, const float* __restrict__ Wproj,
    const float* __restrict__ bproj, const float* __restrict__ gp,
    const float* __restrict__ bp, float* __restrict__ h,
    float* __restrict__ notpad)
{
    const int wave = threadIdx.x >> 6, lane = threadIdx.x & 63;
    const int tok = (blockIdx.x << 2) + wave;     // 0..B*S-1
    const int s = tok & (Sc - 1);
    const float x0 = x[tok * 3 + 0], x1 = x[tok * 3 + 1], x2 = x[tok * 3 + 2];
    if (lane == 0)
        notpad[tok] = (fabsf(x0) + fabsf(x1) + fabsf(x2) == 0.0f) ? 0.0f : 1.0f;
    const float c = -logf(10000.0f) / (float)Dc;
    float v[8];
    float sum = 0.f, sumsq = 0.f;
    #pragma unroll
    for (int g = 0; g < 2; ++g) {
        const int dbase = (g << 8) + (lane << 2);
        #pragma unroll
        for (int j = 0; j < 4; ++j) {
            const int d = dbase + j;
            float val = fmaf(x0, Wproj[d],
                        fmaf(x1, Wproj[Dc + d],
                        fmaf(x2, Wproj[2 * Dc + d], bproj[d])));
            const float arg = (float)s * expf((float)(d & ~1) * c);
            val += (d & 1) ? cosf(arg) : sinf(arg);
            v[(g << 2) + j] = val;
            sum += val; sumsq += val * val;
        }
    }
    #pragma unroll
    for (int m = 1; m < 64; m <<= 1) {
        sum   += __shfl_xor(sum, m, 64);
        sumsq += __shfl_xor(sumsq, m, 64);
    }
    const float mu = sum * (1.0f / Dc);
    const float var = sumsq * (1.0f / Dc) - mu * mu;
    const float rstd = rsqrtf(var + 1e-5f);
    #pragma unroll
    for (int g = 0; g < 2; ++g) {
        const int dbase = (g << 8) + (lane << 2);
        float gg[4], bb[4];
        ld4(gg, gp + dbase); ld4(bb, bp + dbase);
        float4 r;
        r.x = (v[(g<<2)+0] - mu) * rstd * gg[0] + bb[0];
        r.y = (v[(g<<2)+1] - mu) * rstd * gg[1] + bb[1];
        r.z = (v[(g<<2)+2] - mu) * rstd * gg[2] + bb[2];
        r.w = (v[(g<<2)+3] - mu) * rstd * gg[3] + bb[3];
        *(float4*)(h + (size_t)tok * Dc + dbase) = r;
    }
}

// ---------------- residual add + layernorm (delta==nullptr: plain LN) ----
__global__ __launch_bounds__(256) void add_ln(
    const float* __restrict__ hin, const float* __restrict__ delta,
    const float* __restrict__ g, const float* __restrict__ b,
    float* __restrict__ hout)
{
    const int wave = threadIdx.x >> 6, lane = threadIdx.x & 63;
    const int tok = (blockIdx.x << 2) + wave;
    const float* hp = hin + (size_t)tok * Dc;
    float v[8];
    float sum = 0.f, sumsq = 0.f;
    #pragma unroll
    for (int gI = 0; gI < 2; ++gI) {
        const int dbase = (gI << 8) + (lane << 2);
        float a[4];
        ld4(a, hp + dbase);
        if (delta) {
            float d4[4];
            ld4(d4, delta + (size_t)tok * Dc + dbase);
            a[0] += d4[0]; a[1] += d4[1]; a[2] += d4[2]; a[3] += d4[3];
        }
        #pragma unroll
        for (int j = 0; j < 4; ++j) {
            v[(gI << 2) + j] = a[j];
            sum += a[j]; sumsq += a[j] * a[j];
        }
    }
    #pragma unroll
    for (int m = 1; m < 64; m <<= 1) {
        sum   += __shfl_xor(sum, m, 64);
        sumsq += __shfl_xor(sumsq, m, 64);
    }
    const float mu = sum * (1.0f / Dc);
    const float var = sumsq * (1.0f / Dc) - mu * mu;
    const float rstd = rsqrtf(var + 1e-5f);
    #pragma unroll
    for (int gI = 0; gI < 2; ++gI) {
        const int dbase = (gI << 8) + (lane << 2);
        float gg[4], bb[4];
        ld4(gg, g + dbase); ld4(bb, b + dbase);
        float4 r;
        r.x = (v[(gI<<2)+0] - mu) * rstd * gg[0] + bb[0];
        r.y = (v[(gI<<2)+1] - mu) * rstd * gg[1] + bb[1];
        r.z = (v[(gI<<2)+2] - mu) * rstd * gg[2] + bb[2];
        r.w = (v[(gI<<2)+3] - mu) * rstd * gg[3] + bb[3];
        *(float4*)(hout + (size_t)tok * Dc + dbase) = r;
    }
}

// ---------------- fp32 GEMM: C[M,N] = epi(A[M,K] @ W[K,N]) ---------------
// 64x64 tile, BK=16, 256 threads, 4x4 microtile
template<int EPI>   // 0 = none, 1 = silu
__global__ __launch_bounds__(256) void gemm64(
    const float* __restrict__ A, const float* __restrict__ W,
    float* __restrict__ C, int M, int N, int K)
{
    __shared__ float As[16][64];   // k-major
    __shared__ float Ws[16][64];
    const int tid = threadIdx.x;
    const int m0 = blockIdx.y << 6;
    const int n0 = blockIdx.x << 6;
    const int tr = tid >> 4, tc = tid & 15;
    const int arow = tid >> 2, akc = (tid & 3) << 2;
    const int wrow = tid >> 4, wnc = (tid & 15) << 2;
    float acc[4][4] = {};
    for (int k0 = 0; k0 < K; k0 += 16) {
        const float4 av = *(const float4*)(A + (size_t)(m0 + arow) * K + (k0 + akc));
        const float4 wv = *(const float4*)(W + (size_t)(k0 + wrow) * N + (n0 + wnc));
        __syncthreads();
        As[akc + 0][arow] = av.x;
        As[akc + 1][arow] = av.y;
        As[akc + 2][arow] = av.z;
        As[akc + 3][arow] = av.w;
        *(float4*)&Ws[wrow][wnc] = wv;
        __syncthreads();
        #pragma unroll
        for (int kk = 0; kk < 16; ++kk) {
            float a[4], w[4];
            ld4(a, &As[kk][tr << 2]);
            ld4(w, &Ws[kk][tc << 2]);
            #pragma unroll
            for (int i = 0; i < 4; ++i)
                #pragma unroll
                for (int j = 0; j < 4; ++j)
                    acc[i][j] = fmaf(a[i], w[j], acc[i][j]);
        }
    }
    #pragma unroll
    for (int i = 0; i < 4; ++i) {
        float4 r;
        float rv[4];
        #pragma unroll
        for (int j = 0; j < 4; ++j) {
            float vv = acc[i][j];
            if (EPI == 1) vv = vv / (1.0f + expf(-vv));
            rv[j] = vv;
        }
        r.x = rv[0]; r.y = rv[1]; r.z = rv[2]; r.w = rv[3];
        *(float4*)(C + (size_t)(m0 + (tr << 2) + i) * N + n0 + (tc << 2)) = r;
    }
}

// ---------------- flash attention, DH=64, fp32 ---------------------------
// block = 256 threads, one (b, head, 64-query tile); K^T staged in LDS,
// P reuses the K buffer so static LDS stays under 64 KB.
__global__ __launch_bounds__(256) void attn64(
    const float* __restrict__ q, const float* __restrict__ k,
    const float* __restrict__ vp, const float* __restrict__ notpad,
    float* __restrict__ o)
{
    constexpr int PADW = 68;
    __shared__ float Qs[64][PADW];     // [qrow][d], pre-scaled by 1/8
    __shared__ float KtPs[64][PADW];   // phase 1: K^T [d][kcol]; phase 2: P [qrow][kcol]
    __shared__ float Vs[64][PADW];     // [kcol][d]
    __shared__ float npf[64];
    const int tid = threadIdx.x;
    const int qt = blockIdx.x & 15;
    const int hh = (blockIdx.x >> 4) & 7;
    const int b  = blockIdx.x >> 7;
    const int q0 = qt << 6;
    const int tr = tid >> 4, tc = tid & 15;

    #pragma unroll
    for (int it = 0; it < 4; ++it) {
        const int idx = (it << 8) + tid;
        const int r = idx >> 4, c4 = (idx & 15) << 2;
        float4 t4 = *(const float4*)(q + (size_t)((b << 10) + q0 + r) * Dc + (hh << 6) + c4);
        t4.x *= 0.125f; t4.y *= 0.125f; t4.z *= 0.125f; t4.w *= 0.125f;
        *(float4*)&Qs[r][c4] = t4;
    }
    float m_i[4], l_i[4], oacc[4][4] = {};
    #pragma unroll
    for (int i = 0; i < 4; ++i) { m_i[i] = -INFINITY; l_i[i] = 0.0f; }

    for (int kt = 0; kt < 16; ++kt) {
        const int k0 = kt << 6;
        __syncthreads();   // previous PV / Q-load done before overwriting KtPs, Vs
        #pragma unroll
        for (int it = 0; it < 4; ++it) {
            const int idx = (it << 8) + tid;
            const int r = idx >> 4, c4 = (idx & 15) << 2;
            const size_t row = (size_t)((b << 10) + k0 + r) * Dc + (hh << 6) + c4;
            const float4 kv = *(const float4*)(k + row);
            KtPs[c4 + 0][r] = kv.x;
            KtPs[c4 + 1][r] = kv.y;
            KtPs[c4 + 2][r] = kv.z;
            KtPs[c4 + 3][r] = kv.w;
            *(float4*)&Vs[r][c4] = *(const float4*)(vp + row);
        }
        if (tid < 64) npf[tid] = notpad[(b << 10) + k0 + tid];
        __syncthreads();

        // S = Q @ K^T  (scaled via Q)
        float sc[4][4] = {};
        #pragma unroll
        for (int d4 = 0; d4 < 64; d4 += 4) {
            float qa[4][4], ka[4][4];
            #pragma unroll
            for (int i = 0; i < 4; ++i)  ld4(qa[i], &Qs[(tr << 2) + i][d4]);
            #pragma unroll
            for (int dd = 0; dd < 4; ++dd) ld4(ka[dd], &KtPs[d4 + dd][tc << 2]);
            #pragma unroll
            for (int dd = 0; dd < 4; ++dd)
                #pragma unroll
                for (int i = 0; i < 4; ++i)
                    #pragma unroll
                    for (int j = 0; j < 4; ++j)
                        sc[i][j] = fmaf(qa[i][dd], ka[dd][j], sc[i][j]);
        }

        // online softmax (rows owned by 16 consecutive lanes of one wave)
        bool msk[4];
        #pragma unroll
        for (int j = 0; j < 4; ++j) msk[j] = (npf[(tc << 2) + j] == 0.0f);
        float p[4][4];
        #pragma unroll
        for (int i = 0; i < 4; ++i) {
            float tm = -INFINITY;
            #pragma unroll
            for (int j = 0; j < 4; ++j) {
                if (msk[j]) sc[i][j] = -INFINITY;
                tm = fmaxf(tm, sc[i][j]);
            }
            #pragma unroll
            for (int m = 1; m < 16; m <<= 1) tm = fmaxf(tm, __shfl_xor(tm, m, 64));
            const float mn = fmaxf(m_i[i], tm);
            const float alpha = (mn == -INFINITY) ? 1.0f : expf(m_i[i] - mn);
            float rs = 0.0f;
            #pragma unroll
            for (int j = 0; j < 4; ++j) {
                const float pv = msk[j] ? 0.0f : expf(sc[i][j] - mn);
                p[i][j] = pv; rs += pv;
            }
            #pragma unroll
            for (int m = 1; m < 16; m <<= 1) rs += __shfl_xor(rs, m, 64);
            l_i[i] = l_i[i] * alpha + rs;
            m_i[i] = mn;
            #pragma unroll
            for (int j = 0; j < 4; ++j) oacc[i][j] *= alpha;
        }
        __syncthreads();   // all K^T reads done; safe to overwrite with P
        #pragma unroll
        for (int i = 0; i < 4; ++i) {
            float4 r; r.x = p[i][0]; r.y = p[i][1]; r.z = p[i][2]; r.w = p[i][3];
            *(float4*)&KtPs[(tr << 2) + i][tc << 2] = r;
        }
        __syncthreads();

        // O += P @ V
        #pragma unroll
        for (int k4 = 0; k4 < 64; k4 += 4) {
            float pa[4][4], va[4][4];
            #pragma unroll
            for (int i = 0; i < 4; ++i)   ld4(pa[i], &KtPs[(tr << 2) + i][k4]);
            #pragma unroll
            for (int kk = 0; kk < 4; ++kk) ld4(va[kk], &Vs[k4 + kk][tc << 2]);
            #pragma unroll
            for (int kk = 0; kk < 4; ++kk)
                #pragma unroll
                for (int i = 0; i < 4; ++i)
                    #pragma unroll
                    for (int j = 0; j < 4; ++j)
                        oacc[i][j] = fmaf(pa[i][kk], va[kk][j], oacc[i][j]);
        }
    }
    #pragma unroll
    for (int i = 0; i < 4; ++i) {
        float4 r;
        r.x = oacc[i][0] / l_i[i];
        r.y = oacc[i][1] / l_i[i];
        r.z = oacc[i][2] / l_i[i];
        r.w = oacc[i][3] / l_i[i];
        *(float4*)(o + (size_t)((b << 10) + q0 + (tr << 2) + i) * Dc + (hh << 6) + (tc << 2)) = r;
    }
}

// ---------------- masked mean pool (stage: partial sums via atomics) -----
__global__ __launch_bounds__(256) void pool_kernel(
    const float* __restrict__ h, const float* __restrict__ notpad,
    float* __restrict__ pooled, float* __restrict__ counts)
{
    const int b = blockIdx.y;
    const int s0 = blockIdx.x << 5;
    const int t = threadIdx.x;
    float a0 = 0.f, a1 = 0.f;
    for (int ss = 0; ss < 32; ++ss) {
        const float w = notpad[(b << 10) + s0 + ss];
        const float* hp = h + (size_t)((b << 10) + s0 + ss) * Dc;
        a0 = fmaf(w, hp[t], a0);
        a1 = fmaf(w, hp[t + 256], a1);
    }
    atomicAdd(&pooled[b * Dc + t], a0);
    atomicAdd(&pooled[b * Dc + t + 256], a1);
    if (t < 32) {
        float w = notpad[(b << 10) + s0 + t];
        #pragma unroll
        for (int m = 1; m < 32; m <<= 1) w += __shfl_xor(w, m, 64);
        if (t == 0) atomicAdd(&counts[b], w);
    }
}

// ---------------- final tiny GEMV: out = pooled @ Wout + bout ------------
__global__ void out_kernel(
    const float* __restrict__ pooled, const float* __restrict__ counts,
    const float* __restrict__ Wout, const float* __restrict__ bout,
    float* __restrict__ out)
{
    const int bo = blockIdx.x;
    const int b = bo / OUTc, oc = bo % OUTc;
    const int lane = threadIdx.x;
    float acc = 0.f;
    for (int d = lane; d < Dc; d += 64)
        acc = fmaf(pooled[b * Dc + d], Wout[(size_t)d * OUTc + oc], acc);
    #pragma unroll
    for (int m = 1; m < 64; m <<= 1) acc += __shfl_xor(acc, m, 64);
    if (lane == 0) out[b * OUTc + oc] = acc / (counts[b] + 1e-8f) + bout[oc];
}

} // namespace

extern "C" void kernel_launch(void* const* d_in, const int* in_sizes, int n_in,
                              void* d_out, int out_size, void* d_ws, size_t ws_size,
                              hipStream_t stream)
{
    (void)in_sizes; (void)n_in; (void)out_size; (void)ws_size;
    const float* x     = (const float*)d_in[0];
    const float* Wproj = (const float*)d_in[1];
    const float* bproj = (const float*)d_in[2];
    const float* gp    = (const float*)d_in[3];
    const float* bp    = (const float*)d_in[4];
    const float* Wq    = (const float*)d_in[5];
    const float* Wk    = (const float*)d_in[6];
    const float* Wv    = (const float*)d_in[7];
    const float* Wo    = (const float*)d_in[8];
    const float* g1    = (const float*)d_in[9];
    const float* b1    = (const float*)d_in[10];
    const float* W1    = (const float*)d_in[11];
    const float* W2    = (const float*)d_in[12];
    const float* g2    = (const float*)d_in[13];
    const float* b2    = (const float*)d_in[14];
    const float* gf    = (const float*)d_in[15];
    const float* bf    = (const float*)d_in[16];
    const float* Wout  = (const float*)d_in[17];
    const float* bout  = (const float*)d_in[18];
    float* out = (float*)d_out;

    const size_t tok = (size_t)Bc * Sc;              // 8192
    float* ws     = (float*)d_ws;
    float* h      = ws;                              // tok*D          (16 MB)
    float* bufA   = h + tok * Dc;                    // tok*FF         (64 MB)
    float* bufB   = bufA + tok * FFc;                // tok*D          (16 MB)
    float* notpad = bufB + tok * Dc;                 // tok
    float* pooled = notpad + tok;                    // B*D
    float* counts = pooled + (size_t)Bc * Dc;        // B

    float* qb = bufA;
    float* kb = bufA + tok * Dc;
    float* vb = bufA + 2 * tok * Dc;
    float* ob = bufA + 3 * tok * Dc;

    const int M = (int)tok;
    proj_pe_ln<<<M / 4, 256, 0, stream>>>(x, Wproj, bproj, gp, bp, h, notpad);

    for (int l = 0; l < Lc; ++l) {
        const size_t wOff = (size_t)l * Dc * Dc;
        gemm64<0><<<dim3(Dc / 64, M / 64), 256, 0, stream>>>(h,  Wq + wOff, qb, M, Dc, Dc);
        gemm64<0><<<dim3(Dc / 64, M / 64), 256, 0, stream>>>(h,  Wk + wOff, kb, M, Dc, Dc);
        gemm64<0><<<dim3(Dc / 64, M / 64), 256, 0, stream>>>(h,  Wv + wOff, vb, M, Dc, Dc);
        attn64<<<Bc * Hc * (Sc / 64), 256, 0, stream>>>(qb, kb, vb, notpad, ob);
        gemm64<0><<<dim3(Dc / 64, M / 64), 256, 0, stream>>>(ob, Wo + wOff, bufB, M, Dc, Dc);
        add_ln<<<M / 4, 256, 0, stream>>>(h, bufB, g1 + (size_t)l * Dc, b1 + (size_t)l * Dc, h);
        gemm64<1><<<dim3(FFc / 64, M / 64), 256, 0, stream>>>(h, W1 + (size_t)l * Dc * FFc, bufA, M, FFc, Dc);
        gemm64<0><<<dim3(Dc / 64, M / 64), 256, 0, stream>>>(bufA, W2 + (size_t)l * FFc * Dc, bufB, M, Dc, FFc);
        add_ln<<<M / 4, 256, 0, stream>>>(h, bufB, g2 + (size_t)l * Dc, b2 + (size_t)l * Dc, h);
    }
    add_ln<<<M / 4, 256, 0, stream>>>(h, nullptr, gf, bf, h);

    hipMemsetAsync(pooled, 0, (size_t)(Bc * Dc + Bc) * sizeof(float), stream);
    pool_kernel<<<dim3(Sc / 32, Bc), 256, 0, stream>>>(h, notpad, pooled, counts);
    out_kernel<<<Bc * OUTc, 64, 0, stream>>>(pooled, counts, Wout, bout, out);
}

// Round 2
// 1975.980 us; speedup vs baseline: 2.1703x; 2.1703x over previous
//
#include <hip/hip_runtime.h>
#include <math.h>
#include <stdint.h>

namespace {

constexpr int Bc = 8, Sc = 1024, Dc = 512, Hc = 8, FFc = 2048, Lc = 4, OUTc = 6;
constexpr int QS = 1536;   // fused qkv activation row stride

typedef __attribute__((ext_vector_type(8))) short  bf16x8;
typedef __attribute__((ext_vector_type(4))) float  f32x4;
typedef __attribute__((ext_vector_type(8))) unsigned short us8;

__device__ __forceinline__ void ld4(float d[4], const float* s) {
    float4 t = *(const float4*)s;
    d[0] = t.x; d[1] = t.y; d[2] = t.z; d[3] = t.w;
}
__device__ __forceinline__ float bf2f(unsigned short u) {
    union { uint32_t i; float f; } c; c.i = ((uint32_t)u) << 16; return c.f;
}
__device__ __forceinline__ unsigned short f2bf(float f) {
    union { float f; uint32_t i; } c; c.f = f;
    uint32_t r = c.i + 0x7FFF + ((c.i >> 16) & 1);
    return (unsigned short)(r >> 16);
}

#define GLDS16(gp, lp) __builtin_amdgcn_global_load_lds(                      \
    (const __attribute__((address_space(1))) uint32_t*)(gp),                  \
    (__attribute__((address_space(3))) uint32_t*)(lp), 16, 0, 0)

// ---------------- weight transpose + cast: out[n][k] = bf16(in[k][n]) ----
__global__ __launch_bounds__(256) void castT(
    const float* __restrict__ in, unsigned short* __restrict__ out,
    int K, int N, size_t in_ls, size_t out_ls)
{
    __shared__ float t[64][65];
    const int k0 = blockIdx.x << 6, n0 = blockIdx.y << 6;
    in  += (size_t)blockIdx.z * in_ls;
    out += (size_t)blockIdx.z * out_ls;
    const int c = threadIdx.x & 63, r4 = threadIdx.x >> 6;
    #pragma unroll
    for (int it = 0; it < 16; ++it) {
        const int r = (it << 2) + r4;
        t[r][c] = in[(size_t)(k0 + r) * N + n0 + c];
    }
    __syncthreads();
    #pragma unroll
    for (int it = 0; it < 16; ++it) {
        const int r = (it << 2) + r4;           // n index
        out[(size_t)(n0 + r) * K + k0 + c] = f2bf(t[c][r]);
    }
}

// ---------------- proj + positional encoding + layernorm ----------------
__global__ __launch_bounds__(256) void proj_pe_ln(
    const float* __restrict__ x, const float* __restrict__ Wproj,
    const float* __restrict__ bproj, const float* __restrict__ gp,
    const float* __restrict__ bp, float* __restrict__ h,
    unsigned short* __restrict__ hbf, float* __restrict__ notpad)
{
    const int wave = threadIdx.x >> 6, lane = threadIdx.x & 63;
    const int tok = (blockIdx.x << 2) + wave;
    const int s = tok & (Sc - 1);
    const float x0 = x[tok * 3 + 0], x1 = x[tok * 3 + 1], x2 = x[tok * 3 + 2];
    if (lane == 0)
        notpad[tok] = (fabsf(x0) + fabsf(x1) + fabsf(x2) == 0.0f) ? 0.0f : 1.0f;
    const float c = -logf(10000.0f) / (float)Dc;
    float v[8];
    float sum = 0.f, sumsq = 0.f;
    #pragma unroll
    for (int g = 0; g < 2; ++g) {
        const int dbase = (g << 8) + (lane << 2);
        #pragma unroll
        for (int j = 0; j < 4; ++j) {
            const int d = dbase + j;
            float val = fmaf(x0, Wproj[d],
                        fmaf(x1, Wproj[Dc + d],
                        fmaf(x2, Wproj[2 * Dc + d], bproj[d])));
            const float arg = (float)s * expf((float)(d & ~1) * c);
            val += (d & 1) ? cosf(arg) : sinf(arg);
            v[(g << 2) + j] = val;
            sum += val; sumsq += val * val;
        }
    }
    #pragma unroll
    for (int m = 1; m < 64; m <<= 1) {
        sum   += __shfl_xor(sum, m, 64);
        sumsq += __shfl_xor(sumsq, m, 64);
    }
    const float mu = sum * (1.0f / Dc);
    const float var = sumsq * (1.0f / Dc) - mu * mu;
    const float rstd = rsqrtf(var + 1e-5f);
    #pragma unroll
    for (int g = 0; g < 2; ++g) {
        const int dbase = (g << 8) + (lane << 2);
        float gg[4], bb[4];
        ld4(gg, gp + dbase); ld4(bb, bp + dbase);
        float4 r;
        r.x = (v[(g<<2)+0] - mu) * rstd * gg[0] + bb[0];
        r.y = (v[(g<<2)+1] - mu) * rstd * gg[1] + bb[1];
        r.z = (v[(g<<2)+2] - mu) * rstd * gg[2] + bb[2];
        r.w = (v[(g<<2)+3] - mu) * rstd * gg[3] + bb[3];
        *(float4*)(h + (size_t)tok * Dc + dbase) = r;
        ushort4 rb;
        rb.x = f2bf(r.x); rb.y = f2bf(r.y); rb.z = f2bf(r.z); rb.w = f2bf(r.w);
        *(ushort4*)(hbf + (size_t)tok * Dc + dbase) = rb;
    }
}

// ---------------- residual add + layernorm ------------------------------
__global__ __launch_bounds__(256) void add_ln(
    const float* __restrict__ hin, const float* __restrict__ delta,
    const float* __restrict__ g, const float* __restrict__ b,
    float* __restrict__ hout, unsigned short* __restrict__ hbf)
{
    const int wave = threadIdx.x >> 6, lane = threadIdx.x & 63;
    const int tok = (blockIdx.x << 2) + wave;
    const float* hp = hin + (size_t)tok * Dc;
    float v[8];
    float sum = 0.f, sumsq = 0.f;
    #pragma unroll
    for (int gI = 0; gI < 2; ++gI) {
        const int dbase = (gI << 8) + (lane << 2);
        float a[4];
        ld4(a, hp + dbase);
        if (delta) {
            float d4[4];
            ld4(d4, delta + (size_t)tok * Dc + dbase);
            a[0] += d4[0]; a[1] += d4[1]; a[2] += d4[2]; a[3] += d4[3];
        }
        #pragma unroll
        for (int j = 0; j < 4; ++j) {
            v[(gI << 2) + j] = a[j];
            sum += a[j]; sumsq += a[j] * a[j];
        }
    }
    #pragma unroll
    for (int m = 1; m < 64; m <<= 1) {
        sum   += __shfl_xor(sum, m, 64);
        sumsq += __shfl_xor(sumsq, m, 64);
    }
    const float mu = sum * (1.0f / Dc);
    const float var = sumsq * (1.0f / Dc) - mu * mu;
    const float rstd = rsqrtf(var + 1e-5f);
    #pragma unroll
    for (int gI = 0; gI < 2; ++gI) {
        const int dbase = (gI << 8) + (lane << 2);
        float gg[4], bb[4];
        ld4(gg, g + dbase); ld4(bb, b + dbase);
        float4 r;
        r.x = (v[(gI<<2)+0] - mu) * rstd * gg[0] + bb[0];
        r.y = (v[(gI<<2)+1] - mu) * rstd * gg[1] + bb[1];
        r.z = (v[(gI<<2)+2] - mu) * rstd * gg[2] + bb[2];
        r.w = (v[(gI<<2)+3] - mu) * rstd * gg[3] + bb[3];
        *(float4*)(hout + (size_t)tok * Dc + dbase) = r;
        if (hbf) {
            ushort4 rb;
            rb.x = f2bf(r.x); rb.y = f2bf(r.y); rb.z = f2bf(r.z); rb.w = f2bf(r.w);
            *(ushort4*)(hbf + (size_t)tok * Dc + dbase) = rb;
        }
    }
}

// ---------------- bf16 MFMA GEMM: C[M,N] = epi(A[M,K] @ Bt[N,K]^T) -------
// m97 structure: 128x128 tile, BK=32, 256 threads (4 waves, 2x2 of 64x64),
// global_load_lds width-16 staging, 16x16x32 bf16 MFMA.
// EPI: 0 = fp32 out, 1 = silu + bf16 out, 2 = bf16 out
template<int EPI>
__global__ __launch_bounds__(256) void gemm_bf16(
    const unsigned short* __restrict__ A, const unsigned short* __restrict__ Bt,
    void* __restrict__ Cv, int M, int N, int K)
{
    __shared__ unsigned short As[128 * 32];   // [m][k] row-major, 64 B/row
    __shared__ unsigned short Bs[128 * 32];   // [n][k] row-major
    const int tid = threadIdx.x;
    const int wave = tid >> 6, lane = tid & 63;
    const int m0 = blockIdx.y << 7, n0 = blockIdx.x << 7;
    const int wm = (wave >> 1) << 6, wn = (wave & 1) << 6;
    const int lrow = lane >> 2;          // 0..15 within a 16-row group
    const int lcol = (lane & 3) << 3;    // element offset 0,8,16,24
    const int l15 = lane & 15;
    const int krow = (lane >> 4) << 3;   // k-slice 0,8,16,24

    f32x4 acc[4][4] = {};

    for (int k0 = 0; k0 < K; k0 += 32) {
        __syncthreads();
        #pragma unroll
        for (int t = 0; t < 2; ++t) {
            const int rbase = (t << 6) + (wave << 4);
            GLDS16(A  + (size_t)(m0 + rbase + lrow) * K + k0 + lcol, &As[rbase * 32]);
            GLDS16(Bt + (size_t)(n0 + rbase + lrow) * K + k0 + lcol, &Bs[rbase * 32]);
        }
        __syncthreads();
        bf16x8 af[4], bfr[4];
        #pragma unroll
        for (int i = 0; i < 4; ++i)
            af[i] = *(const bf16x8*)&As[(wm + (i << 4) + l15) * 32 + krow];
        #pragma unroll
        for (int j = 0; j < 4; ++j)
            bfr[j] = *(const bf16x8*)&Bs[(wn + (j << 4) + l15) * 32 + krow];
        #pragma unroll
        for (int i = 0; i < 4; ++i)
            #pragma unroll
            for (int j = 0; j < 4; ++j)
                acc[i][j] = __builtin_amdgcn_mfma_f32_16x16x32_bf16(
                    af[i], bfr[j], acc[i][j], 0, 0, 0);
    }

    const int crow0 = m0 + wm + ((lane >> 4) << 2);
    const int ccol0 = n0 + wn + l15;
    #pragma unroll
    for (int i = 0; i < 4; ++i)
        #pragma unroll
        for (int j = 0; j < 4; ++j)
            #pragma unroll
            for (int r = 0; r < 4; ++r) {
                const int row = crow0 + (i << 4) + r;
                const int col = ccol0 + (j << 4);
                float v = acc[i][j][r];
                if (EPI == 0) {
                    ((float*)Cv)[(size_t)row * N + col] = v;
                } else {
                    if (EPI == 1) v = v / (1.0f + expf(-v));
                    ((unsigned short*)Cv)[(size_t)row * N + col] = f2bf(v);
                }
            }
}

// ---------------- flash attention, DH=64, bf16 in / bf16 out -------------
__global__ __launch_bounds__(256) void attn64(
    const unsigned short* __restrict__ qkv, const float* __restrict__ notpad,
    unsigned short* __restrict__ o)
{
    constexpr int PADW = 68;
    __shared__ float Qs[64][PADW];     // [qrow][d], pre-scaled by 1/8
    __shared__ float KtPs[64][PADW];   // phase 1: K^T [d][kcol]; phase 2: P
    __shared__ float Vs[64][PADW];     // [kcol][d]
    __shared__ float npf[64];
    const int tid = threadIdx.x;
    const int qt = blockIdx.x & 15;
    const int hh = (blockIdx.x >> 4) & 7;
    const int b  = blockIdx.x >> 7;
    const int q0 = qt << 6;
    const int tr = tid >> 4, tc = tid & 15;

    #pragma unroll
    for (int it = 0; it < 2; ++it) {
        const int idx = (it << 8) + tid;
        const int r = idx >> 3, c8 = (idx & 7) << 3;
        const us8 qv = *(const us8*)(qkv + (size_t)((b << 10) + q0 + r) * QS + (hh << 6) + c8);
        float4 a, bb;
        a.x  = bf2f(qv[0]) * 0.125f; a.y  = bf2f(qv[1]) * 0.125f;
        a.z  = bf2f(qv[2]) * 0.125f; a.w  = bf2f(qv[3]) * 0.125f;
        bb.x = bf2f(qv[4]) * 0.125f; bb.y = bf2f(qv[5]) * 0.125f;
        bb.z = bf2f(qv[6]) * 0.125f; bb.w = bf2f(qv[7]) * 0.125f;
        *(float4*)&Qs[r][c8] = a;
        *(float4*)&Qs[r][c8 + 4] = bb;
    }
    float m_i[4], l_i[4], oacc[4][4] = {};
    #pragma unroll
    for (int i = 0; i < 4; ++i) { m_i[i] = -INFINITY; l_i[i] = 0.0f; }

    for (int kt = 0; kt < 16; ++kt) {
        const int k0 = kt << 6;
        __syncthreads();
        #pragma unroll
        for (int it = 0; it < 2; ++it) {
            const int idx = (it << 8) + tid;
            const int r = idx >> 3, c8 = (idx & 7) << 3;
            const size_t rowoff = (size_t)((b << 10) + k0 + r) * QS + (hh << 6) + c8;
            const us8 kv = *(const us8*)(qkv + 512 + rowoff);
            const us8 vv = *(const us8*)(qkv + 1024 + rowoff);
            #pragma unroll
            for (int j = 0; j < 8; ++j) KtPs[c8 + j][r] = bf2f(kv[j]);
            float4 a, bb;
            a.x  = bf2f(vv[0]); a.y  = bf2f(vv[1]); a.z  = bf2f(vv[2]); a.w  = bf2f(vv[3]);
            bb.x = bf2f(vv[4]); bb.y = bf2f(vv[5]); bb.z = bf2f(vv[6]); bb.w = bf2f(vv[7]);
            *(float4*)&Vs[r][c8] = a;
            *(float4*)&Vs[r][c8 + 4] = bb;
        }
        if (tid < 64) npf[tid] = notpad[(b << 10) + k0 + tid];
        __syncthreads();

        float sc[4][4] = {};
        #pragma unroll
        for (int d4 = 0; d4 < 64; d4 += 4) {
            float qa[4][4], ka[4][4];
            #pragma unroll
            for (int i = 0; i < 4; ++i)  ld4(qa[i], &Qs[(tr << 2) + i][d4]);
            #pragma unroll
            for (int dd = 0; dd < 4; ++dd) ld4(ka[dd], &KtPs[d4 + dd][tc << 2]);
            #pragma unroll
            for (int dd = 0; dd < 4; ++dd)
                #pragma unroll
                for (int i = 0; i < 4; ++i)
                    #pragma unroll
                    for (int j = 0; j < 4; ++j)
                        sc[i][j] = fmaf(qa[i][dd], ka[dd][j], sc[i][j]);
        }

        bool msk[4];
        #pragma unroll
        for (int j = 0; j < 4; ++j) msk[j] = (npf[(tc << 2) + j] == 0.0f);
        float p[4][4];
        #pragma unroll
        for (int i = 0; i < 4; ++i) {
            float tm = -INFINITY;
            #pragma unroll
            for (int j = 0; j < 4; ++j) {
                if (msk[j]) sc[i][j] = -INFINITY;
                tm = fmaxf(tm, sc[i][j]);
            }
            #pragma unroll
            for (int m = 1; m < 16; m <<= 1) tm = fmaxf(tm, __shfl_xor(tm, m, 64));
            const float mn = fmaxf(m_i[i], tm);
            const float alpha = (mn == -INFINITY) ? 1.0f : expf(m_i[i] - mn);
            float rs = 0.0f;
            #pragma unroll
            for (int j = 0; j < 4; ++j) {
                const float pv = msk[j] ? 0.0f : expf(sc[i][j] - mn);
                p[i][j] = pv; rs += pv;
            }
            #pragma unroll
            for (int m = 1; m < 16; m <<= 1) rs += __shfl_xor(rs, m, 64);
            l_i[i] = l_i[i] * alpha + rs;
            m_i[i] = mn;
            #pragma unroll
            for (int j = 0; j < 4; ++j) oacc[i][j] *= alpha;
        }
        __syncthreads();
        #pragma unroll
        for (int i = 0; i < 4; ++i) {
            float4 r; r.x = p[i][0]; r.y = p[i][1]; r.z = p[i][2]; r.w = p[i][3];
            *(float4*)&KtPs[(tr << 2) + i][tc << 2] = r;
        }
        __syncthreads();

        #pragma unroll
        for (int k4 = 0; k4 < 64; k4 += 4) {
            float pa[4][4], va[4][4];
            #pragma unroll
            for (int i = 0; i < 4; ++i)   ld4(pa[i], &KtPs[(tr << 2) + i][k4]);
            #pragma unroll
            for (int kk = 0; kk < 4; ++kk) ld4(va[kk], &Vs[k4 + kk][tc << 2]);
            #pragma unroll
            for (int kk = 0; kk < 4; ++kk)
                #pragma unroll
                for (int i = 0; i < 4; ++i)
                    #pragma unroll
                    for (int j = 0; j < 4; ++j)
                        oacc[i][j] = fmaf(pa[i][kk], va[kk][j], oacc[i][j]);
        }
    }
    #pragma unroll
    for (int i = 0; i < 4; ++i) {
        ushort4 r4;
        r4.x = f2bf(oacc[i][0] / l_i[i]);
        r4.y = f2bf(oacc[i][1] / l_i[i]);
        r4.z = f2bf(oacc[i][2] / l_i[i]);
        r4.w = f2bf(oacc[i][3] / l_i[i]);
        *(ushort4*)(o + (size_t)((b << 10) + q0 + (tr << 2) + i) * Dc + (hh << 6) + (tc << 2)) = r4;
    }
}

// ---------------- masked mean pool ---------------------------------------
__global__ __launch_bounds__(256) void pool_kernel(
    const float* __restrict__ h, const float* __restrict__ notpad,
    float* __restrict__ pooled, float* __restrict__ counts)
{
    const int b = blockIdx.y;
    const int s0 = blockIdx.x << 5;
    const int t = threadIdx.x;
    float a0 = 0.f, a1 = 0.f;
    for (int ss = 0; ss < 32; ++ss) {
        const float w = notpad[(b << 10) + s0 + ss];
        const float* hp = h + (size_t)((b << 10) + s0 + ss) * Dc;
        a0 = fmaf(w, hp[t], a0);
        a1 = fmaf(w, hp[t + 256], a1);
    }
    atomicAdd(&pooled[b * Dc + t], a0);
    atomicAdd(&pooled[b * Dc + t + 256], a1);
    if (t < 32) {
        float w = notpad[(b << 10) + s0 + t];
        #pragma unroll
        for (int m = 1; m < 32; m <<= 1) w += __shfl_xor(w, m, 64);
        if (t == 0) atomicAdd(&counts[b], w);
    }
}

// ---------------- final tiny GEMV ----------------------------------------
__global__ void out_kernel(
    const float* __restrict__ pooled, const float* __restrict__ counts,
    const float* __restrict__ Wout, const float* __restrict__ bout,
    float* __restrict__ out)
{
    const int bo = blockIdx.x;
    const int b = bo / OUTc, oc = bo % OUTc;
    const int lane = threadIdx.x;
    float acc = 0.f;
    for (int d = lane; d < Dc; d += 64)
        acc = fmaf(pooled[b * Dc + d], Wout[(size_t)d * OUTc + oc], acc);
    #pragma unroll
    for (int m = 1; m < 64; m <<= 1) acc += __shfl_xor(acc, m, 64);
    if (lane == 0) out[b * OUTc + oc] = acc / (counts[b] + 1e-8f) + bout[oc];
}

} // namespace

extern "C" void kernel_launch(void* const* d_in, const int* in_sizes, int n_in,
                              void* d_out, int out_size, void* d_ws, size_t ws_size,
                              hipStream_t stream)
{
    (void)in_sizes; (void)n_in; (void)out_size; (void)ws_size;
    const float* x     = (const float*)d_in[0];
    const float* Wproj = (const float*)d_in[1];
    const float* bproj = (const float*)d_in[2];
    const float* gp    = (const float*)d_in[3];
    const float* bp    = (const float*)d_in[4];
    const float* Wq    = (const float*)d_in[5];
    const float* Wk    = (const float*)d_in[6];
    const float* Wv    = (const float*)d_in[7];
    const float* Wo    = (const float*)d_in[8];
    const float* g1    = (const float*)d_in[9];
    const float* b1    = (const float*)d_in[10];
    const float* W1    = (const float*)d_in[11];
    const float* W2    = (const float*)d_in[12];
    const float* g2    = (const float*)d_in[13];
    const float* b2    = (const float*)d_in[14];
    const float* gf    = (const float*)d_in[15];
    const float* bf    = (const float*)d_in[16];
    const float* Wout  = (const float*)d_in[17];
    const float* bout  = (const float*)d_in[18];
    float* out = (float*)d_out;

    const size_t MiB = 1u << 20;
    char* base = (char*)d_ws;
    float*          h      = (float*)(base);                 // 16 MiB
    unsigned short* h_bf   = (unsigned short*)(base + 16 * MiB);   // 8 MiB
    char*           big    = base + 24 * MiB;                // 32 MiB shared
    float*          bufB   = (float*)(base + 56 * MiB);      // 16 MiB
    unsigned short* qkvT   = (unsigned short*)(base + 72 * MiB);   // 6 MiB
    unsigned short* WoT    = (unsigned short*)(base + 78 * MiB);   // 2 MiB
    unsigned short* W1T    = (unsigned short*)(base + 80 * MiB);   // 8 MiB
    unsigned short* W2T    = (unsigned short*)(base + 88 * MiB);   // 8 MiB
    float*          notpad = (float*)(base + 96 * MiB);      // 32 KiB
    float*          pooled = notpad + 8192;                  // 16 KiB
    float*          counts = pooled + Bc * Dc;

    unsigned short* qkv_act = (unsigned short*)big;            // 24 MiB [tok][1536]
    unsigned short* ob_bf   = (unsigned short*)(big + 24 * MiB); // 8 MiB [tok][512]
    unsigned short* ffa_bf  = (unsigned short*)big;            // 32 MiB [tok][2048]

    const int M = Bc * Sc;   // 8192

    // weight transpose+cast (per-call; ~12 us total)
    castT<<<dim3(8, 8, Lc), 256, 0, stream>>>(Wq, qkvT,               512, 512, (size_t)512*512, (size_t)QS*512);
    castT<<<dim3(8, 8, Lc), 256, 0, stream>>>(Wk, qkvT + 512 * 512,   512, 512, (size_t)512*512, (size_t)QS*512);
    castT<<<dim3(8, 8, Lc), 256, 0, stream>>>(Wv, qkvT + 1024 * 512,  512, 512, (size_t)512*512, (size_t)QS*512);
    castT<<<dim3(8, 8, Lc), 256, 0, stream>>>(Wo, WoT,                512, 512, (size_t)512*512, (size_t)512*512);
    castT<<<dim3(8, 32, Lc), 256, 0, stream>>>(W1, W1T, 512, 2048, (size_t)512*2048, (size_t)2048*512);
    castT<<<dim3(32, 8, Lc), 256, 0, stream>>>(W2, W2T, 2048, 512, (size_t)2048*512, (size_t)512*2048);

    proj_pe_ln<<<M / 4, 256, 0, stream>>>(x, Wproj, bproj, gp, bp, h, h_bf, notpad);

    for (int l = 0; l < Lc; ++l) {
        gemm_bf16<2><<<dim3(QS / 128, M / 128), 256, 0, stream>>>(
            h_bf, qkvT + (size_t)l * QS * 512, qkv_act, M, QS, 512);
        attn64<<<Bc * Hc * (Sc / 64), 256, 0, stream>>>(qkv_act, notpad, ob_bf);
        gemm_bf16<0><<<dim3(512 / 128, M / 128), 256, 0, stream>>>(
            ob_bf, WoT + (size_t)l * 512 * 512, bufB, M, 512, 512);
        add_ln<<<M / 4, 256, 0, stream>>>(h, bufB, g1 + (size_t)l * Dc, b1 + (size_t)l * Dc, h, h_bf);
        gemm_bf16<1><<<dim3(FFc / 128, M / 128), 256, 0, stream>>>(
            h_bf, W1T + (size_t)l * FFc * 512, ffa_bf, M, FFc, 512);
        gemm_bf16<0><<<dim3(512 / 128, M / 128), 256, 0, stream>>>(
            ffa_bf, W2T + (size_t)l * 512 * FFc, bufB, M, 512, FFc);
        add_ln<<<M / 4, 256, 0, stream>>>(h, bufB, g2 + (size_t)l * Dc, b2 + (size_t)l * Dc, h, h_bf);
    }
    add_ln<<<M / 4, 256, 0, stream>>>(h, nullptr, gf, bf, h, nullptr);

    hipMemsetAsync(pooled, 0, (size_t)(Bc * Dc + Bc) * sizeof(float), stream);
    pool_kernel<<<dim3(Sc / 32, Bc), 256, 0, stream>>>(h, notpad, pooled, counts);
    out_kernel<<<Bc * OUTc, 64, 0, stream>>>(pooled, counts, Wout, bout, out);
}

// Round 3
// 1029.895 us; speedup vs baseline: 4.1640x; 1.9186x over previous
//
#include <hip/hip_runtime.h>
#include <math.h>
#include <stdint.h>

namespace {

constexpr int Bc = 8, Sc = 1024, Dc = 512, Hc = 8, FFc = 2048, Lc = 4, OUTc = 6;
constexpr int QS = 1536;   // fused qkv weight col count

typedef __attribute__((ext_vector_type(8))) short  bf16x8;
typedef __attribute__((ext_vector_type(4))) float  f32x4;

__device__ __forceinline__ void ld4(float d[4], const float* s) {
    float4 t = *(const float4*)s;
    d[0] = t.x; d[1] = t.y; d[2] = t.z; d[3] = t.w;
}
__device__ __forceinline__ unsigned short f2bf(float f) {
    union { float f; uint32_t i; } c; c.f = f;
    uint32_t r = c.i + 0x7FFF + ((c.i >> 16) & 1);
    return (unsigned short)(r >> 16);
}

#define GLDS16(gp, lp) __builtin_amdgcn_global_load_lds(                      \
    (const __attribute__((address_space(1))) uint32_t*)(gp),                  \
    (__attribute__((address_space(3))) uint32_t*)(lp), 16, 0, 0)

// ---------------- weight transpose + cast: out[n][k] = bf16(in[k][n]) ----
__global__ __launch_bounds__(256) void castT(
    const float* __restrict__ in, unsigned short* __restrict__ out,
    int K, int N, size_t in_ls, size_t out_ls)
{
    __shared__ float t[64][65];
    const int k0 = blockIdx.x << 6, n0 = blockIdx.y << 6;
    in  += (size_t)blockIdx.z * in_ls;
    out += (size_t)blockIdx.z * out_ls;
    const int c = threadIdx.x & 63, r4 = threadIdx.x >> 6;
    #pragma unroll
    for (int it = 0; it < 16; ++it) {
        const int r = (it << 2) + r4;
        t[r][c] = in[(size_t)(k0 + r) * N + n0 + c];
    }
    __syncthreads();
    #pragma unroll
    for (int it = 0; it < 16; ++it) {
        const int r = (it << 2) + r4;           // n index
        out[(size_t)(n0 + r) * K + k0 + c] = f2bf(t[c][r]);
    }
}

// ---------------- proj + positional encoding + layernorm ----------------
__global__ __launch_bounds__(256) void proj_pe_ln(
    const float* __restrict__ x, const float* __restrict__ Wproj,
    const float* __restrict__ bproj, const float* __restrict__ gp,
    const float* __restrict__ bp, float* __restrict__ h,
    unsigned short* __restrict__ hbf, float* __restrict__ notpad)
{
    const int wave = threadIdx.x >> 6, lane = threadIdx.x & 63;
    const int tok = (blockIdx.x << 2) + wave;
    const int s = tok & (Sc - 1);
    const float x0 = x[tok * 3 + 0], x1 = x[tok * 3 + 1], x2 = x[tok * 3 + 2];
    if (lane == 0)
        notpad[tok] = (fabsf(x0) + fabsf(x1) + fabsf(x2) == 0.0f) ? 0.0f : 1.0f;
    const float c = -logf(10000.0f) / (float)Dc;
    float v[8];
    float sum = 0.f, sumsq = 0.f;
    #pragma unroll
    for (int g = 0; g < 2; ++g) {
        const int dbase = (g << 8) + (lane << 2);
        #pragma unroll
        for (int j = 0; j < 4; ++j) {
            const int d = dbase + j;
            float val = fmaf(x0, Wproj[d],
                        fmaf(x1, Wproj[Dc + d],
                        fmaf(x2, Wproj[2 * Dc + d], bproj[d])));
            const float arg = (float)s * expf((float)(d & ~1) * c);
            val += (d & 1) ? cosf(arg) : sinf(arg);
            v[(g << 2) + j] = val;
            sum += val; sumsq += val * val;
        }
    }
    #pragma unroll
    for (int m = 1; m < 64; m <<= 1) {
        sum   += __shfl_xor(sum, m, 64);
        sumsq += __shfl_xor(sumsq, m, 64);
    }
    const float mu = sum * (1.0f / Dc);
    const float var = sumsq * (1.0f / Dc) - mu * mu;
    const float rstd = rsqrtf(var + 1e-5f);
    #pragma unroll
    for (int g = 0; g < 2; ++g) {
        const int dbase = (g << 8) + (lane << 2);
        float gg[4], bb[4];
        ld4(gg, gp + dbase); ld4(bb, bp + dbase);
        float4 r;
        r.x = (v[(g<<2)+0] - mu) * rstd * gg[0] + bb[0];
        r.y = (v[(g<<2)+1] - mu) * rstd * gg[1] + bb[1];
        r.z = (v[(g<<2)+2] - mu) * rstd * gg[2] + bb[2];
        r.w = (v[(g<<2)+3] - mu) * rstd * gg[3] + bb[3];
        *(float4*)(h + (size_t)tok * Dc + dbase) = r;
        ushort4 rb;
        rb.x = f2bf(r.x); rb.y = f2bf(r.y); rb.z = f2bf(r.z); rb.w = f2bf(r.w);
        *(ushort4*)(hbf + (size_t)tok * Dc + dbase) = rb;
    }
}

// ---------------- residual add + layernorm ------------------------------
__global__ __launch_bounds__(256) void add_ln(
    const float* __restrict__ hin, const float* __restrict__ delta,
    const float* __restrict__ g, const float* __restrict__ b,
    float* __restrict__ hout, unsigned short* __restrict__ hbf)
{
    const int wave = threadIdx.x >> 6, lane = threadIdx.x & 63;
    const int tok = (blockIdx.x << 2) + wave;
    const float* hp = hin + (size_t)tok * Dc;
    float v[8];
    float sum = 0.f, sumsq = 0.f;
    #pragma unroll
    for (int gI = 0; gI < 2; ++gI) {
        const int dbase = (gI << 8) + (lane << 2);
        float a[4];
        ld4(a, hp + dbase);
        if (delta) {
            float d4[4];
            ld4(d4, delta + (size_t)tok * Dc + dbase);
            a[0] += d4[0]; a[1] += d4[1]; a[2] += d4[2]; a[3] += d4[3];
        }
        #pragma unroll
        for (int j = 0; j < 4; ++j) {
            v[(gI << 2) + j] = a[j];
            sum += a[j]; sumsq += a[j] * a[j];
        }
    }
    #pragma unroll
    for (int m = 1; m < 64; m <<= 1) {
        sum   += __shfl_xor(sum, m, 64);
        sumsq += __shfl_xor(sumsq, m, 64);
    }
    const float mu = sum * (1.0f / Dc);
    const float var = sumsq * (1.0f / Dc) - mu * mu;
    const float rstd = rsqrtf(var + 1e-5f);
    #pragma unroll
    for (int gI = 0; gI < 2; ++gI) {
        const int dbase = (gI << 8) + (lane << 2);
        float gg[4], bb[4];
        ld4(gg, g + dbase); ld4(bb, b + dbase);
        float4 r;
        r.x = (v[(gI<<2)+0] - mu) * rstd * gg[0] + bb[0];
        r.y = (v[(gI<<2)+1] - mu) * rstd * gg[1] + bb[1];
        r.z = (v[(gI<<2)+2] - mu) * rstd * gg[2] + bb[2];
        r.w = (v[(gI<<2)+3] - mu) * rstd * gg[3] + bb[3];
        *(float4*)(hout + (size_t)tok * Dc + dbase) = r;
        if (hbf) {
            ushort4 rb;
            rb.x = f2bf(r.x); rb.y = f2bf(r.y); rb.z = f2bf(r.z); rb.w = f2bf(r.w);
            *(ushort4*)(hbf + (size_t)tok * Dc + dbase) = rb;
        }
    }
}

// ---------------- bf16 MFMA GEMM: C[M,N] = epi(A[M,K] @ Bt[N,K]^T) -------
// EPI: 0 = fp32 out, 1 = silu + bf16 out, 2 = bf16 out,
//      3 = qkv: n<1024 -> bf16 row-major (stride 1024) to Cv,
//               n>=1024 -> bf16 transposed vT[bh][dh][s] to Cv2
template<int EPI>
__global__ __launch_bounds__(256) void gemm_bf16(
    const unsigned short* __restrict__ A, const unsigned short* __restrict__ Bt,
    void* __restrict__ Cv, void* __restrict__ Cv2, int M, int N, int K)
{
    __shared__ unsigned short As[128 * 32];   // [m][k] row-major, 64 B/row
    __shared__ unsigned short Bs[128 * 32];   // [n][k] row-major
    const int tid = threadIdx.x;
    const int wave = tid >> 6, lane = tid & 63;
    const int m0 = blockIdx.y << 7, n0 = blockIdx.x << 7;
    const int wm = (wave >> 1) << 6, wn = (wave & 1) << 6;
    const int lrow = lane >> 2;          // 0..15 within a 16-row group
    const int lcol = (lane & 3) << 3;    // element offset 0,8,16,24
    const int l15 = lane & 15;
    const int krow = (lane >> 4) << 3;   // k-slice 0,8,16,24

    f32x4 acc[4][4] = {};

    for (int k0 = 0; k0 < K; k0 += 32) {
        __syncthreads();
        #pragma unroll
        for (int t = 0; t < 2; ++t) {
            const int rbase = (t << 6) + (wave << 4);
            GLDS16(A  + (size_t)(m0 + rbase + lrow) * K + k0 + lcol, &As[rbase * 32]);
            GLDS16(Bt + (size_t)(n0 + rbase + lrow) * K + k0 + lcol, &Bs[rbase * 32]);
        }
        __syncthreads();
        bf16x8 af[4], bfr[4];
        #pragma unroll
        for (int i = 0; i < 4; ++i)
            af[i] = *(const bf16x8*)&As[(wm + (i << 4) + l15) * 32 + krow];
        #pragma unroll
        for (int j = 0; j < 4; ++j)
            bfr[j] = *(const bf16x8*)&Bs[(wn + (j << 4) + l15) * 32 + krow];
        #pragma unroll
        for (int i = 0; i < 4; ++i)
            #pragma unroll
            for (int j = 0; j < 4; ++j)
                acc[i][j] = __builtin_amdgcn_mfma_f32_16x16x32_bf16(
                    af[i], bfr[j], acc[i][j], 0, 0, 0);
    }

    const int crow0 = m0 + wm + ((lane >> 4) << 2);
    const int ccol0 = n0 + wn + l15;
    #pragma unroll
    for (int i = 0; i < 4; ++i)
        #pragma unroll
        for (int j = 0; j < 4; ++j)
            #pragma unroll
            for (int r = 0; r < 4; ++r) {
                const int row = crow0 + (i << 4) + r;
                const int col = ccol0 + (j << 4);
                float v = acc[i][j][r];
                if (EPI == 0) {
                    ((float*)Cv)[(size_t)row * N + col] = v;
                } else if (EPI == 3) {
                    if (n0 < 1024) {
                        ((unsigned short*)Cv)[(size_t)row * 1024 + col] = f2bf(v);
                    } else {
                        const int head = (col - 1024) >> 6, dh = col & 63;
                        const int bb = row >> 10, ss = row & 1023;
                        ((unsigned short*)Cv2)[
                            ((size_t)(((bb << 3) + head) << 6) + dh) * 1024 + ss] = f2bf(v);
                    }
                } else {
                    if (EPI == 1) v = v / (1.0f + expf(-v));
                    ((unsigned short*)Cv)[(size_t)row * N + col] = f2bf(v);
                }
            }
}

// ---------------- MFMA flash attention, DH=64 ----------------------------
// block = 256 threads (4 waves); one (b, head, 64-query tile) per block.
// wave w owns q rows [16w, 16w+16). K/V staged per 64-key tile via
// global_load_lds; P round-trips through wave-private LDS to convert
// MFMA C-layout -> A-operand layout.
__global__ __launch_bounds__(256) void attn_mfma(
    const unsigned short* __restrict__ qk,   // [8192][1024] bf16, q | k
    const unsigned short* __restrict__ vT,   // [64 bh][64 dh][1024 s] bf16
    const float* __restrict__ notpad,
    unsigned short* __restrict__ o)          // [8192][512] bf16
{
    __shared__ unsigned short Ks[2][64][32];  // panel p: dh 32p..32p+31, rows=key
    __shared__ unsigned short Vs[2][64][32];  // panel p: keys 32p..32p+31, rows=dh
    __shared__ unsigned short Ps[4][16][80];  // per-wave P, rows=q, cols=key
    __shared__ float npf[64];
    const int tid = threadIdx.x;
    const int wave = tid >> 6, lane = tid & 63;
    const int qt = blockIdx.x & 15;
    const int hh = (blockIdx.x >> 4) & 7;
    const int b  = blockIdx.x >> 7;
    const int q0 = qt << 6;
    const int l15 = lane & 15, lg = lane >> 4;
    const int srow = lane >> 2;               // staging row within 16-group
    const int scol = (lane & 3) << 3;         // staging col (elements)

    // ---- stage Q tile into Ks (reused), pull A-fragments into registers
    #pragma unroll
    for (int p = 0; p < 2; ++p)
        GLDS16(qk + (size_t)((b << 10) + q0 + (wave << 4) + srow) * 1024
                  + (hh << 6) + (p << 5) + scol,
               &Ks[p][wave << 4][0]);
    __syncthreads();
    bf16x8 qf[2];
    qf[0] = *(const bf16x8*)&Ks[0][(wave << 4) + l15][lg << 3];
    qf[1] = *(const bf16x8*)&Ks[1][(wave << 4) + l15][lg << 3];

    f32x4 oacc[4] = {};
    float m_i[4], l_i[4];
    #pragma unroll
    for (int r = 0; r < 4; ++r) { m_i[r] = -INFINITY; l_i[r] = 0.0f; }

    for (int kt = 0; kt < 16; ++kt) {
        const int k0 = kt << 6;
        __syncthreads();   // previous iteration's fragment reads (and qf load) done
        #pragma unroll
        for (int p = 0; p < 2; ++p) {
            GLDS16(qk + (size_t)((b << 10) + k0 + (wave << 4) + srow) * 1024
                      + 512 + (hh << 6) + (p << 5) + scol,
                   &Ks[p][wave << 4][0]);
            GLDS16(vT + (size_t)(((b << 3) + hh) * 64 + (wave << 4) + srow) * 1024
                      + k0 + (p << 5) + scol,
                   &Vs[p][wave << 4][0]);
        }
        if (tid < 64) npf[tid] = notpad[(b << 10) + k0 + tid];
        __syncthreads();

        // ---- S = Q K^T (16 q x 64 keys per wave)
        f32x4 sacc[4];
        #pragma unroll
        for (int j = 0; j < 4; ++j) {
            sacc[j] = (f32x4){0.f, 0.f, 0.f, 0.f};
            const bf16x8 kf0 = *(const bf16x8*)&Ks[0][(j << 4) + l15][lg << 3];
            const bf16x8 kf1 = *(const bf16x8*)&Ks[1][(j << 4) + l15][lg << 3];
            sacc[j] = __builtin_amdgcn_mfma_f32_16x16x32_bf16(qf[0], kf0, sacc[j], 0, 0, 0);
            sacc[j] = __builtin_amdgcn_mfma_f32_16x16x32_bf16(qf[1], kf1, sacc[j], 0, 0, 0);
        }

        // ---- scale + mask + online softmax (row = (lg<<2)+r, col = 16j+l15)
        bool mskv[4];
        #pragma unroll
        for (int j = 0; j < 4; ++j) mskv[j] = (npf[(j << 4) + l15] == 0.0f);
        float sc[4][4];
        #pragma unroll
        for (int j = 0; j < 4; ++j)
            #pragma unroll
            for (int r = 0; r < 4; ++r)
                sc[j][r] = mskv[j] ? -INFINITY : sacc[j][r] * 0.125f;

        float pv[4][4];
        #pragma unroll
        for (int r = 0; r < 4; ++r) {
            float tm = fmaxf(fmaxf(sc[0][r], sc[1][r]), fmaxf(sc[2][r], sc[3][r]));
            #pragma unroll
            for (int m = 1; m < 16; m <<= 1) tm = fmaxf(tm, __shfl_xor(tm, m, 64));
            const float mn = fmaxf(m_i[r], tm);
            const float alpha = (mn == -INFINITY) ? 1.0f : __expf(m_i[r] - mn);
            float rs = 0.f;
            #pragma unroll
            for (int j = 0; j < 4; ++j) {
                const float e = mskv[j] ? 0.0f : __expf(sc[j][r] - mn);
                pv[j][r] = e; rs += e;
            }
            #pragma unroll
            for (int m = 1; m < 16; m <<= 1) rs += __shfl_xor(rs, m, 64);
            l_i[r] = l_i[r] * alpha + rs;
            m_i[r] = mn;
            #pragma unroll
            for (int j = 0; j < 4; ++j) oacc[j][r] *= alpha;
        }

        // ---- P: C-layout -> A-layout via wave-private LDS
        #pragma unroll
        for (int j = 0; j < 4; ++j)
            #pragma unroll
            for (int r = 0; r < 4; ++r)
                Ps[wave][(lg << 2) + r][(j << 4) + l15] = f2bf(pv[j][r]);
        __asm__ volatile("s_waitcnt lgkmcnt(0)" ::: "memory");
        const bf16x8 pa0 = *(const bf16x8*)&Ps[wave][l15][lg << 3];
        const bf16x8 pa1 = *(const bf16x8*)&Ps[wave][l15][32 + (lg << 3)];

        // ---- O += P V
        #pragma unroll
        for (int j = 0; j < 4; ++j) {
            const bf16x8 vf0 = *(const bf16x8*)&Vs[0][(j << 4) + l15][lg << 3];
            const bf16x8 vf1 = *(const bf16x8*)&Vs[1][(j << 4) + l15][lg << 3];
            oacc[j] = __builtin_amdgcn_mfma_f32_16x16x32_bf16(pa0, vf0, oacc[j], 0, 0, 0);
            oacc[j] = __builtin_amdgcn_mfma_f32_16x16x32_bf16(pa1, vf1, oacc[j], 0, 0, 0);
        }
    }

    const int tokr = (b << 10) + q0 + (wave << 4) + (lg << 2);
    float inv[4];
    #pragma unroll
    for (int r = 0; r < 4; ++r) inv[r] = 1.0f / l_i[r];
    #pragma unroll
    for (int j = 0; j < 4; ++j)
        #pragma unroll
        for (int r = 0; r < 4; ++r)
            o[(size_t)(tokr + r) * 512 + (hh << 6) + (j << 4) + l15] =
                f2bf(oacc[j][r] * inv[r]);
}

// ---------------- masked mean pool ---------------------------------------
__global__ __launch_bounds__(256) void pool_kernel(
    const float* __restrict__ h, const float* __restrict__ notpad,
    float* __restrict__ pooled, float* __restrict__ counts)
{
    const int b = blockIdx.y;
    const int s0 = blockIdx.x << 5;
    const int t = threadIdx.x;
    float a0 = 0.f, a1 = 0.f;
    for (int ss = 0; ss < 32; ++ss) {
        const float w = notpad[(b << 10) + s0 + ss];
        const float* hp = h + (size_t)((b << 10) + s0 + ss) * Dc;
        a0 = fmaf(w, hp[t], a0);
        a1 = fmaf(w, hp[t + 256], a1);
    }
    atomicAdd(&pooled[b * Dc + t], a0);
    atomicAdd(&pooled[b * Dc + t + 256], a1);
    if (t < 32) {
        float w = notpad[(b << 10) + s0 + t];
        #pragma unroll
        for (int m = 1; m < 32; m <<= 1) w += __shfl_xor(w, m, 64);
        if (t == 0) atomicAdd(&counts[b], w);
    }
}

// ---------------- final tiny GEMV ----------------------------------------
__global__ void out_kernel(
    const float* __restrict__ pooled, const float* __restrict__ counts,
    const float* __restrict__ Wout, const float* __restrict__ bout,
    float* __restrict__ out)
{
    const int bo = blockIdx.x;
    const int b = bo / OUTc, oc = bo % OUTc;
    const int lane = threadIdx.x;
    float acc = 0.f;
    for (int d = lane; d < Dc; d += 64)
        acc = fmaf(pooled[b * Dc + d], Wout[(size_t)d * OUTc + oc], acc);
    #pragma unroll
    for (int m = 1; m < 64; m <<= 1) acc += __shfl_xor(acc, m, 64);
    if (lane == 0) out[b * OUTc + oc] = acc / (counts[b] + 1e-8f) + bout[oc];
}

} // namespace

extern "C" void kernel_launch(void* const* d_in, const int* in_sizes, int n_in,
                              void* d_out, int out_size, void* d_ws, size_t ws_size,
                              hipStream_t stream)
{
    (void)in_sizes; (void)n_in; (void)out_size; (void)ws_size;
    const float* x     = (const float*)d_in[0];
    const float* Wproj = (const float*)d_in[1];
    const float* bproj = (const float*)d_in[2];
    const float* gp    = (const float*)d_in[3];
    const float* bp    = (const float*)d_in[4];
    const float* Wq    = (const float*)d_in[5];
    const float* Wk    = (const float*)d_in[6];
    const float* Wv    = (const float*)d_in[7];
    const float* Wo    = (const float*)d_in[8];
    const float* g1    = (const float*)d_in[9];
    const float* b1    = (const float*)d_in[10];
    const float* W1    = (const float*)d_in[11];
    const float* W2    = (const float*)d_in[12];
    const float* g2    = (const float*)d_in[13];
    const float* b2    = (const float*)d_in[14];
    const float* gf    = (const float*)d_in[15];
    const float* bf    = (const float*)d_in[16];
    const float* Wout  = (const float*)d_in[17];
    const float* bout  = (const float*)d_in[18];
    float* out = (float*)d_out;

    const size_t MiB = 1u << 20;
    char* base = (char*)d_ws;
    float*          h      = (float*)(base);                       // 16 MiB
    unsigned short* h_bf   = (unsigned short*)(base + 16 * MiB);   // 8 MiB
    unsigned short* qk_act = (unsigned short*)(base + 24 * MiB);   // 16 MiB [8192][1024]
    unsigned short* vT     = (unsigned short*)(base + 40 * MiB);   // 8 MiB [64][64][1024]
    unsigned short* ob_bf  = (unsigned short*)(base + 48 * MiB);   // 8 MiB [8192][512]
    float*          bufB   = (float*)(base + 56 * MiB);            // 16 MiB
    unsigned short* ffa_bf = (unsigned short*)(base + 24 * MiB);   // 32 MiB (aliases qk/vT/ob)
    unsigned short* qkvT   = (unsigned short*)(base + 72 * MiB);   // 6 MiB
    unsigned short* WoT    = (unsigned short*)(base + 78 * MiB);   // 2 MiB
    unsigned short* W1T    = (unsigned short*)(base + 80 * MiB);   // 8 MiB
    unsigned short* W2T    = (unsigned short*)(base + 88 * MiB);   // 8 MiB
    float*          notpad = (float*)(base + 96 * MiB);            // 32 KiB
    float*          pooled = notpad + 8192;
    float*          counts = pooled + Bc * Dc;

    const int M = Bc * Sc;   // 8192

    // weight transpose+cast (per-call)
    castT<<<dim3(8, 8, Lc), 256, 0, stream>>>(Wq, qkvT,               512, 512, (size_t)512*512, (size_t)QS*512);
    castT<<<dim3(8, 8, Lc), 256, 0, stream>>>(Wk, qkvT + 512 * 512,   512, 512, (size_t)512*512, (size_t)QS*512);
    castT<<<dim3(8, 8, Lc), 256, 0, stream>>>(Wv, qkvT + 1024 * 512,  512, 512, (size_t)512*512, (size_t)QS*512);
    castT<<<dim3(8, 8, Lc), 256, 0, stream>>>(Wo, WoT,                512, 512, (size_t)512*512, (size_t)512*512);
    castT<<<dim3(8, 32, Lc), 256, 0, stream>>>(W1, W1T, 512, 2048, (size_t)512*2048, (size_t)2048*512);
    castT<<<dim3(32, 8, Lc), 256, 0, stream>>>(W2, W2T, 2048, 512, (size_t)2048*512, (size_t)512*2048);

    proj_pe_ln<<<M / 4, 256, 0, stream>>>(x, Wproj, bproj, gp, bp, h, h_bf, notpad);

    for (int l = 0; l < Lc; ++l) {
        gemm_bf16<3><<<dim3(QS / 128, M / 128), 256, 0, stream>>>(
            h_bf, qkvT + (size_t)l * QS * 512, qk_act, vT, M, QS, 512);
        attn_mfma<<<Bc * Hc * (Sc / 64), 256, 0, stream>>>(qk_act, vT, notpad, ob_bf);
        gemm_bf16<0><<<dim3(512 / 128, M / 128), 256, 0, stream>>>(
            ob_bf, WoT + (size_t)l * 512 * 512, bufB, nullptr, M, 512, 512);
        add_ln<<<M / 4, 256, 0, stream>>>(h, bufB, g1 + (size_t)l * Dc, b1 + (size_t)l * Dc, h, h_bf);
        gemm_bf16<1><<<dim3(FFc / 128, M / 128), 256, 0, stream>>>(
            h_bf, W1T + (size_t)l * FFc * 512, ffa_bf, nullptr, M, FFc, 512);
        gemm_bf16<0><<<dim3(512 / 128, M / 128), 256, 0, stream>>>(
            ffa_bf, W2T + (size_t)l * 512 * FFc, bufB, nullptr, M, 512, FFc);
        add_ln<<<M / 4, 256, 0, stream>>>(h, bufB, g2 + (size_t)l * Dc, b2 + (size_t)l * Dc, h, h_bf);
    }
    add_ln<<<M / 4, 256, 0, stream>>>(h, nullptr, gf, bf, h, nullptr);

    hipMemsetAsync(pooled, 0, (size_t)(Bc * Dc + Bc) * sizeof(float), stream);
    pool_kernel<<<dim3(Sc / 32, Bc), 256, 0, stream>>>(h, notpad, pooled, counts);
    out_kernel<<<Bc * OUTc, 64, 0, stream>>>(pooled, counts, Wout, bout, out);
}

// Round 4
// 901.233 us; speedup vs baseline: 4.7585x; 1.1428x over previous
//
#include <hip/hip_runtime.h>
#include <math.h>
#include <stdint.h>

namespace {

constexpr int Bc = 8, Sc = 1024, Dc = 512, Hc = 8, FFc = 2048, Lc = 4, OUTc = 6;
constexpr int QS = 1536;   // fused qkv weight col count

typedef __attribute__((ext_vector_type(8))) short  bf16x8;
typedef __attribute__((ext_vector_type(4))) float  f32x4;

__device__ __forceinline__ void ld4(float d[4], const float* s) {
    float4 t = *(const float4*)s;
    d[0] = t.x; d[1] = t.y; d[2] = t.z; d[3] = t.w;
}
__device__ __forceinline__ float bf2f(unsigned short u) {
    union { uint32_t i; float f; } c; c.i = ((uint32_t)u) << 16; return c.f;
}
__device__ __forceinline__ unsigned short f2bf(float f) {
    union { float f; uint32_t i; } c; c.f = f;
    uint32_t r = c.i + 0x7FFF + ((c.i >> 16) & 1);
    return (unsigned short)(r >> 16);
}

#define GLDS16(gp, lp) __builtin_amdgcn_global_load_lds(                      \
    (const __attribute__((address_space(1))) uint32_t*)(gp),                  \
    (__attribute__((address_space(3))) uint32_t*)(lp), 16, 0, 0)

// ---------------- weight transpose + cast: out[n][k] = bf16(in[k][n]) ----
__global__ __launch_bounds__(256) void castT(
    const float* __restrict__ in, unsigned short* __restrict__ out,
    int K, int N, size_t in_ls, size_t out_ls)
{
    __shared__ float t[64][65];
    const int k0 = blockIdx.x << 6, n0 = blockIdx.y << 6;
    in  += (size_t)blockIdx.z * in_ls;
    out += (size_t)blockIdx.z * out_ls;
    const int c = threadIdx.x & 63, r4 = threadIdx.x >> 6;
    #pragma unroll
    for (int it = 0; it < 16; ++it) {
        const int r = (it << 2) + r4;
        t[r][c] = in[(size_t)(k0 + r) * N + n0 + c];
    }
    __syncthreads();
    #pragma unroll
    for (int it = 0; it < 16; ++it) {
        const int r = (it << 2) + r4;           // n index
        out[(size_t)(n0 + r) * K + k0 + c] = f2bf(t[c][r]);
    }
}

// ---------------- proj + positional encoding + layernorm ----------------
__global__ __launch_bounds__(256) void proj_pe_ln(
    const float* __restrict__ x, const float* __restrict__ Wproj,
    const float* __restrict__ bproj, const float* __restrict__ gp,
    const float* __restrict__ bp, float* __restrict__ h,
    unsigned short* __restrict__ hbf, float* __restrict__ notpad,
    float* __restrict__ maskadd)
{
    const int wave = threadIdx.x >> 6, lane = threadIdx.x & 63;
    const int tok = (blockIdx.x << 2) + wave;
    const int s = tok & (Sc - 1);
    const float x0 = x[tok * 3 + 0], x1 = x[tok * 3 + 1], x2 = x[tok * 3 + 2];
    if (lane == 0) {
        const bool pad = (fabsf(x0) + fabsf(x1) + fabsf(x2) == 0.0f);
        notpad[tok]  = pad ? 0.0f : 1.0f;
        maskadd[tok] = pad ? -1e30f : 0.0f;
    }
    const float c = -logf(10000.0f) / (float)Dc;
    float v[8];
    float sum = 0.f, sumsq = 0.f;
    #pragma unroll
    for (int g = 0; g < 2; ++g) {
        const int dbase = (g << 8) + (lane << 2);
        #pragma unroll
        for (int j = 0; j < 4; ++j) {
            const int d = dbase + j;
            float val = fmaf(x0, Wproj[d],
                        fmaf(x1, Wproj[Dc + d],
                        fmaf(x2, Wproj[2 * Dc + d], bproj[d])));
            const float arg = (float)s * expf((float)(d & ~1) * c);
            val += (d & 1) ? cosf(arg) : sinf(arg);
            v[(g << 2) + j] = val;
            sum += val; sumsq += val * val;
        }
    }
    #pragma unroll
    for (int m = 1; m < 64; m <<= 1) {
        sum   += __shfl_xor(sum, m, 64);
        sumsq += __shfl_xor(sumsq, m, 64);
    }
    const float mu = sum * (1.0f / Dc);
    const float var = sumsq * (1.0f / Dc) - mu * mu;
    const float rstd = rsqrtf(var + 1e-5f);
    #pragma unroll
    for (int g = 0; g < 2; ++g) {
        const int dbase = (g << 8) + (lane << 2);
        float gg[4], bb[4];
        ld4(gg, gp + dbase); ld4(bb, bp + dbase);
        float4 r;
        r.x = (v[(g<<2)+0] - mu) * rstd * gg[0] + bb[0];
        r.y = (v[(g<<2)+1] - mu) * rstd * gg[1] + bb[1];
        r.z = (v[(g<<2)+2] - mu) * rstd * gg[2] + bb[2];
        r.w = (v[(g<<2)+3] - mu) * rstd * gg[3] + bb[3];
        *(float4*)(h + (size_t)tok * Dc + dbase) = r;
        ushort4 rb;
        rb.x = f2bf(r.x); rb.y = f2bf(r.y); rb.z = f2bf(r.z); rb.w = f2bf(r.w);
        *(ushort4*)(hbf + (size_t)tok * Dc + dbase) = rb;
    }
}

// ---------------- residual add + layernorm (delta is bf16) ---------------
__global__ __launch_bounds__(256) void add_ln(
    const float* __restrict__ hin, const unsigned short* __restrict__ delta,
    const float* __restrict__ g, const float* __restrict__ b,
    float* __restrict__ hout, unsigned short* __restrict__ hbf)
{
    const int wave = threadIdx.x >> 6, lane = threadIdx.x & 63;
    const int tok = (blockIdx.x << 2) + wave;
    const float* hp = hin + (size_t)tok * Dc;
    float v[8];
    float sum = 0.f, sumsq = 0.f;
    #pragma unroll
    for (int gI = 0; gI < 2; ++gI) {
        const int dbase = (gI << 8) + (lane << 2);
        float a[4];
        ld4(a, hp + dbase);
        if (delta) {
            ushort4 d4 = *(const ushort4*)(delta + (size_t)tok * Dc + dbase);
            a[0] += bf2f(d4.x); a[1] += bf2f(d4.y);
            a[2] += bf2f(d4.z); a[3] += bf2f(d4.w);
        }
        #pragma unroll
        for (int j = 0; j < 4; ++j) {
            v[(gI << 2) + j] = a[j];
            sum += a[j]; sumsq += a[j] * a[j];
        }
    }
    #pragma unroll
    for (int m = 1; m < 64; m <<= 1) {
        sum   += __shfl_xor(sum, m, 64);
        sumsq += __shfl_xor(sumsq, m, 64);
    }
    const float mu = sum * (1.0f / Dc);
    const float var = sumsq * (1.0f / Dc) - mu * mu;
    const float rstd = rsqrtf(var + 1e-5f);
    #pragma unroll
    for (int gI = 0; gI < 2; ++gI) {
        const int dbase = (gI << 8) + (lane << 2);
        float gg[4], bb[4];
        ld4(gg, g + dbase); ld4(bb, b + dbase);
        float4 r;
        r.x = (v[(gI<<2)+0] - mu) * rstd * gg[0] + bb[0];
        r.y = (v[(gI<<2)+1] - mu) * rstd * gg[1] + bb[1];
        r.z = (v[(gI<<2)+2] - mu) * rstd * gg[2] + bb[2];
        r.w = (v[(gI<<2)+3] - mu) * rstd * gg[3] + bb[3];
        *(float4*)(hout + (size_t)tok * Dc + dbase) = r;
        if (hbf) {
            ushort4 rb;
            rb.x = f2bf(r.x); rb.y = f2bf(r.y); rb.z = f2bf(r.z); rb.w = f2bf(r.w);
            *(ushort4*)(hbf + (size_t)tok * Dc + dbase) = rb;
        }
    }
}

// ---------------- bf16 MFMA GEMM: C[M,N] = epi(A[M,K] @ Bt[N,K]^T) -------
// 128xNT tile, BK=32, 256 threads. NT = 128 or 64.
// EPI: 1 = silu + bf16 out, 2 = bf16 out,
//      3 = qkv: n<512 -> q*0.125 bf16 (stride 1024); 512..1023 -> k bf16;
//               n>=1024 -> v transposed via LDS to vT[bh][dh][s] (coalesced)
template<int EPI, int NT>
__global__ __launch_bounds__(256) void gemm_bf16(
    const unsigned short* __restrict__ A, const unsigned short* __restrict__ Bt,
    void* __restrict__ Cv, void* __restrict__ Cv2, int M, int N, int K)
{
    constexpr int JN = NT / 32;               // j-tiles per wave
    __shared__ unsigned short As[128 * 32];   // [m][k] row-major
    __shared__ unsigned short Bs[NT * 32];    // [n][k] row-major
    __shared__ unsigned short Tr[(EPI == 3) ? 128 * 128 : 1];
    const int tid = threadIdx.x;
    const int wave = tid >> 6, lane = tid & 63;
    const int m0 = blockIdx.y << 7;
    const int n0 = blockIdx.x * NT;
    const int wm = (wave >> 1) << 6;
    const int wn = (wave & 1) * (NT / 2);
    const int lrow = lane >> 2;          // 0..15
    const int lcol = (lane & 3) << 3;    // 0,8,16,24
    const int l15 = lane & 15;
    const int lg = lane >> 4;
    const int krow = lg << 3;

    f32x4 acc[4][JN] = {};

    for (int k0 = 0; k0 < K; k0 += 32) {
        __syncthreads();
        #pragma unroll
        for (int t = 0; t < 2; ++t) {
            const int rbase = (t << 6) + (wave << 4);
            GLDS16(A + (size_t)(m0 + rbase + lrow) * K + k0 + lcol, &As[rbase * 32]);
        }
        #pragma unroll
        for (int t = 0; t < NT / 64; ++t) {
            const int rbase = (t << 6) + (wave << 4);
            GLDS16(Bt + (size_t)(n0 + rbase + lrow) * K + k0 + lcol, &Bs[rbase * 32]);
        }
        __syncthreads();
        bf16x8 af[4], bfr[JN];
        #pragma unroll
        for (int i = 0; i < 4; ++i)
            af[i] = *(const bf16x8*)&As[(wm + (i << 4) + l15) * 32 + krow];
        #pragma unroll
        for (int j = 0; j < JN; ++j)
            bfr[j] = *(const bf16x8*)&Bs[(wn + (j << 4) + l15) * 32 + krow];
        #pragma unroll
        for (int i = 0; i < 4; ++i)
            #pragma unroll
            for (int j = 0; j < JN; ++j)
                acc[i][j] = __builtin_amdgcn_mfma_f32_16x16x32_bf16(
                    af[i], bfr[j], acc[i][j], 0, 0, 0);
    }

    if constexpr (EPI == 3) {
        if (n0 >= 1024) {   // V part: transpose via LDS, coalesced b128 writes
            __syncthreads();
            #pragma unroll
            for (int i = 0; i < 4; ++i)
                #pragma unroll
                for (int j = 0; j < JN; ++j)
                    #pragma unroll
                    for (int r = 0; r < 4; ++r) {
                        const int lm = wm + (i << 4) + (lg << 2) + r;
                        const int ln = wn + (j << 4) + l15;
                        Tr[ln * 128 + lm] = f2bf(acc[i][j][r]);
                    }
            __syncthreads();
            const int bb = m0 >> 10, s0 = m0 & 1023;
            #pragma unroll
            for (int it = 0; it < 8; ++it) {
                const int idx = (it << 8) + tid;
                const int ln = idx >> 4, lmc = (idx & 15) << 3;
                const int gcol = n0 - 1024 + ln;
                const int head = gcol >> 6, dh = gcol & 63;
                *(bf16x8*)((unsigned short*)Cv2 +
                    (size_t)((((bb << 3) + head) << 6) + dh) * 1024 + s0 + lmc) =
                    *(const bf16x8*)&Tr[ln * 128 + lmc];
            }
            return;
        }
    }

    const int crow0 = m0 + wm + (lg << 2);
    const int ccol0 = n0 + wn + l15;
    #pragma unroll
    for (int i = 0; i < 4; ++i)
        #pragma unroll
        for (int j = 0; j < JN; ++j)
            #pragma unroll
            for (int r = 0; r < 4; ++r) {
                const int row = crow0 + (i << 4) + r;
                const int col = ccol0 + (j << 4);
                float v = acc[i][j][r];
                if (EPI == 3) {
                    if (n0 < 512) v *= 0.125f;     // fold 1/sqrt(DH) into q
                    ((unsigned short*)Cv)[(size_t)row * 1024 + col] = f2bf(v);
                } else {
                    if (EPI == 1) v = v / (1.0f + expf(-v));
                    ((unsigned short*)Cv)[(size_t)row * N + col] = f2bf(v);
                }
            }
}

// ---------------- MFMA flash attention, DH=64, no-max softmax ------------
// block = 256 threads (4 waves); one (b, head, 64-query tile).
// 128-key iterations; scores tiny (|s|<~3) so exp without max-subtraction
// is safe; l accumulated lane-locally, reduced once at the end.
__global__ __launch_bounds__(256) void attn_mfma(
    const unsigned short* __restrict__ qk,   // [8192][1024] bf16, q*0.125 | k
    const unsigned short* __restrict__ vT,   // [64 bh][64 dh][1024 s] bf16
    const float* __restrict__ maskadd,       // 0 or -1e30 per token
    unsigned short* __restrict__ o)          // [8192][512] bf16
{
    __shared__ unsigned short Ks[2][128][32]; // panel p: dh 32p.., rows=key
    __shared__ unsigned short Vs[4][64][32];  // panel p: keys 32p.., rows=dh
    __shared__ unsigned short Ps[4][16][132]; // per-wave P (padded stride)
    __shared__ float Madd[128];
    const int tid = threadIdx.x;
    const int wave = tid >> 6, lane = tid & 63;
    const int qt = blockIdx.x & 15;
    const int hh = (blockIdx.x >> 4) & 7;
    const int b  = blockIdx.x >> 7;
    const int q0 = qt << 6;
    const int l15 = lane & 15, lg = lane >> 4;
    const int srow = lane >> 2;
    const int scol = (lane & 3) << 3;

    // stage Q tile (64 rows) into Ks rows 0..63; pull A-fragments
    #pragma unroll
    for (int p = 0; p < 2; ++p)
        GLDS16(qk + (size_t)((b << 10) + q0 + (wave << 4) + srow) * 1024
                  + (hh << 6) + (p << 5) + scol,
               &Ks[p][wave << 4][0]);
    __syncthreads();
    bf16x8 qf[2];
    qf[0] = *(const bf16x8*)&Ks[0][(wave << 4) + l15][lg << 3];
    qf[1] = *(const bf16x8*)&Ks[1][(wave << 4) + l15][lg << 3];

    f32x4 oacc[4] = {};
    float l_part[4] = {0.f, 0.f, 0.f, 0.f};

    for (int kt = 0; kt < 8; ++kt) {
        const int k0 = kt << 7;
        __syncthreads();   // previous iteration's fragment reads done
        #pragma unroll
        for (int t = 0; t < 2; ++t) {
            const int rbase = (t << 6) + (wave << 4);
            #pragma unroll
            for (int p = 0; p < 2; ++p)
                GLDS16(qk + (size_t)((b << 10) + k0 + rbase + srow) * 1024
                          + 512 + (hh << 6) + (p << 5) + scol,
                       &Ks[p][rbase][0]);
        }
        #pragma unroll
        for (int p = 0; p < 4; ++p)
            GLDS16(vT + (size_t)(((b << 3) + hh) * 64 + (wave << 4) + srow) * 1024
                      + k0 + (p << 5) + scol,
                   &Vs[p][wave << 4][0]);
        if (tid < 128) Madd[tid] = maskadd[(b << 10) + k0 + tid];
        __syncthreads();

        // S = Q K^T : 16 q x 128 keys per wave (8 column tiles)
        f32x4 sacc[8];
        #pragma unroll
        for (int j = 0; j < 8; ++j) {
            sacc[j] = (f32x4){0.f, 0.f, 0.f, 0.f};
            #pragma unroll
            for (int p = 0; p < 2; ++p) {
                const bf16x8 kf = *(const bf16x8*)&Ks[p][(j << 4) + l15][lg << 3];
                sacc[j] = __builtin_amdgcn_mfma_f32_16x16x32_bf16(qf[p], kf, sacc[j], 0, 0, 0);
            }
        }

        // exp (no max-subtraction), accumulate l, stage P (C-layout -> A-layout)
        #pragma unroll
        for (int j = 0; j < 8; ++j) {
            const float ma = Madd[(j << 4) + l15];
            #pragma unroll
            for (int r = 0; r < 4; ++r) {
                const float p = __expf(sacc[j][r] + ma);
                l_part[r] += p;
                Ps[wave][(lg << 2) + r][(j << 4) + l15] = f2bf(p);
            }
        }
        __asm__ volatile("s_waitcnt lgkmcnt(0)" ::: "memory");

        // O += P V : 4 dh tiles x 4 key panels
        #pragma unroll
        for (int kp = 0; kp < 4; ++kp) {
            const bf16x8 pa = *(const bf16x8*)&Ps[wave][l15][(kp << 5) + (lg << 3)];
            #pragma unroll
            for (int j = 0; j < 4; ++j) {
                const bf16x8 vf = *(const bf16x8*)&Vs[kp][(j << 4) + l15][lg << 3];
                oacc[j] = __builtin_amdgcn_mfma_f32_16x16x32_bf16(pa, vf, oacc[j], 0, 0, 0);
            }
        }
    }

    #pragma unroll
    for (int r = 0; r < 4; ++r) {
        float l = l_part[r];
        #pragma unroll
        for (int m = 1; m < 16; m <<= 1) l += __shfl_xor(l, m, 64);
        l_part[r] = 1.0f / l;
    }
    const int tokr = (b << 10) + q0 + (wave << 4) + (lg << 2);
    #pragma unroll
    for (int j = 0; j < 4; ++j)
        #pragma unroll
        for (int r = 0; r < 4; ++r)
            o[(size_t)(tokr + r) * 512 + (hh << 6) + (j << 4) + l15] =
                f2bf(oacc[j][r] * l_part[r]);
}

// ---------------- masked mean pool ---------------------------------------
__global__ __launch_bounds__(256) void pool_kernel(
    const float* __restrict__ h, const float* __restrict__ notpad,
    float* __restrict__ pooled, float* __restrict__ counts)
{
    const int b = blockIdx.y;
    const int s0 = blockIdx.x << 5;
    const int t = threadIdx.x;
    float a0 = 0.f, a1 = 0.f;
    for (int ss = 0; ss < 32; ++ss) {
        const float w = notpad[(b << 10) + s0 + ss];
        const float* hp = h + (size_t)((b << 10) + s0 + ss) * Dc;
        a0 = fmaf(w, hp[t], a0);
        a1 = fmaf(w, hp[t + 256], a1);
    }
    atomicAdd(&pooled[b * Dc + t], a0);
    atomicAdd(&pooled[b * Dc + t + 256], a1);
    if (t < 32) {
        float w = notpad[(b << 10) + s0 + t];
        #pragma unroll
        for (int m = 1; m < 32; m <<= 1) w += __shfl_xor(w, m, 64);
        if (t == 0) atomicAdd(&counts[b], w);
    }
}

// ---------------- final tiny GEMV ----------------------------------------
__global__ void out_kernel(
    const float* __restrict__ pooled, const float* __restrict__ counts,
    const float* __restrict__ Wout, const float* __restrict__ bout,
    float* __restrict__ out)
{
    const int bo = blockIdx.x;
    const int b = bo / OUTc, oc = bo % OUTc;
    const int lane = threadIdx.x;
    float acc = 0.f;
    for (int d = lane; d < Dc; d += 64)
        acc = fmaf(pooled[b * Dc + d], Wout[(size_t)d * OUTc + oc], acc);
    #pragma unroll
    for (int m = 1; m < 64; m <<= 1) acc += __shfl_xor(acc, m, 64);
    if (lane == 0) out[b * OUTc + oc] = acc / (counts[b] + 1e-8f) + bout[oc];
}

} // namespace

extern "C" void kernel_launch(void* const* d_in, const int* in_sizes, int n_in,
                              void* d_out, int out_size, void* d_ws, size_t ws_size,
                              hipStream_t stream)
{
    (void)in_sizes; (void)n_in; (void)out_size; (void)ws_size;
    const float* x     = (const float*)d_in[0];
    const float* Wproj = (const float*)d_in[1];
    const float* bproj = (const float*)d_in[2];
    const float* gp    = (const float*)d_in[3];
    const float* bp    = (const float*)d_in[4];
    const float* Wq    = (const float*)d_in[5];
    const float* Wk    = (const float*)d_in[6];
    const float* Wv    = (const float*)d_in[7];
    const float* Wo    = (const float*)d_in[8];
    const float* g1    = (const float*)d_in[9];
    const float* b1    = (const float*)d_in[10];
    const float* W1    = (const float*)d_in[11];
    const float* W2    = (const float*)d_in[12];
    const float* g2    = (const float*)d_in[13];
    const float* b2    = (const float*)d_in[14];
    const float* gf    = (const float*)d_in[15];
    const float* bf    = (const float*)d_in[16];
    const float* Wout  = (const float*)d_in[17];
    const float* bout  = (const float*)d_in[18];
    float* out = (float*)d_out;

    const size_t MiB = 1u << 20;
    char* base = (char*)d_ws;
    float*          h       = (float*)(base);                       // 16 MiB
    unsigned short* h_bf    = (unsigned short*)(base + 16 * MiB);   // 8 MiB
    unsigned short* qk_act  = (unsigned short*)(base + 24 * MiB);   // 16 MiB [8192][1024]
    unsigned short* vT      = (unsigned short*)(base + 40 * MiB);   // 8 MiB [64][64][1024]
    unsigned short* ob_bf   = (unsigned short*)(base + 48 * MiB);   // 8 MiB [8192][512]
    unsigned short* bufB_bf = (unsigned short*)(base + 56 * MiB);   // 8 MiB [8192][512]
    unsigned short* ffa_bf  = (unsigned short*)(base + 24 * MiB);   // 32 MiB (aliases qk/vT/ob)
    unsigned short* qkvT    = (unsigned short*)(base + 72 * MiB);   // 6 MiB
    unsigned short* WoT     = (unsigned short*)(base + 78 * MiB);   // 2 MiB
    unsigned short* W1T     = (unsigned short*)(base + 80 * MiB);   // 8 MiB
    unsigned short* W2T     = (unsigned short*)(base + 88 * MiB);   // 8 MiB
    float*          notpad  = (float*)(base + 96 * MiB);            // 32 KiB
    float*          maskadd = notpad + 8192;                        // 32 KiB
    float*          pooled  = maskadd + 8192;
    float*          counts  = pooled + Bc * Dc;

    const int M = Bc * Sc;   // 8192

    // weight transpose+cast (per-call)
    castT<<<dim3(8, 8, Lc), 256, 0, stream>>>(Wq, qkvT,               512, 512, (size_t)512*512, (size_t)QS*512);
    castT<<<dim3(8, 8, Lc), 256, 0, stream>>>(Wk, qkvT + 512 * 512,   512, 512, (size_t)512*512, (size_t)QS*512);
    castT<<<dim3(8, 8, Lc), 256, 0, stream>>>(Wv, qkvT + 1024 * 512,  512, 512, (size_t)512*512, (size_t)QS*512);
    castT<<<dim3(8, 8, Lc), 256, 0, stream>>>(Wo, WoT,                512, 512, (size_t)512*512, (size_t)512*512);
    castT<<<dim3(8, 32, Lc), 256, 0, stream>>>(W1, W1T, 512, 2048, (size_t)512*2048, (size_t)2048*512);
    castT<<<dim3(32, 8, Lc), 256, 0, stream>>>(W2, W2T, 2048, 512, (size_t)2048*512, (size_t)512*2048);

    proj_pe_ln<<<M / 4, 256, 0, stream>>>(x, Wproj, bproj, gp, bp, h, h_bf, notpad, maskadd);

    for (int l = 0; l < Lc; ++l) {
        gemm_bf16<3, 128><<<dim3(QS / 128, M / 128), 256, 0, stream>>>(
            h_bf, qkvT + (size_t)l * QS * 512, qk_act, vT, M, QS, 512);
        attn_mfma<<<Bc * Hc * (Sc / 64), 256, 0, stream>>>(qk_act, vT, maskadd, ob_bf);
        gemm_bf16<2, 64><<<dim3(512 / 64, M / 128), 256, 0, stream>>>(
            ob_bf, WoT + (size_t)l * 512 * 512, bufB_bf, nullptr, M, 512, 512);
        add_ln<<<M / 4, 256, 0, stream>>>(h, bufB_bf, g1 + (size_t)l * Dc, b1 + (size_t)l * Dc, h, h_bf);
        gemm_bf16<1, 128><<<dim3(FFc / 128, M / 128), 256, 0, stream>>>(
            h_bf, W1T + (size_t)l * FFc * 512, ffa_bf, nullptr, M, FFc, 512);
        gemm_bf16<2, 64><<<dim3(512 / 64, M / 128), 256, 0, stream>>>(
            ffa_bf, W2T + (size_t)l * 512 * FFc, bufB_bf, nullptr, M, 512, FFc);
        add_ln<<<M / 4, 256, 0, stream>>>(h, bufB_bf, g2 + (size_t)l * Dc, b2 + (size_t)l * Dc, h, h_bf);
    }
    add_ln<<<M / 4, 256, 0, stream>>>(h, nullptr, gf, bf, h, nullptr);

    hipMemsetAsync(pooled, 0, (size_t)(Bc * Dc + Bc) * sizeof(float), stream);
    pool_kernel<<<dim3(Sc / 32, Bc), 256, 0, stream>>>(h, notpad, pooled, counts);
    out_kernel<<<Bc * OUTc, 64, 0, stream>>>(pooled, counts, Wout, bout, out);
}

// Round 5
// 816.154 us; speedup vs baseline: 5.2545x; 1.1042x over previous
//
#include <hip/hip_runtime.h>
#include <math.h>
#include <stdint.h>

namespace {

constexpr int Bc = 8, Sc = 1024, Dc = 512, Hc = 8, FFc = 2048, Lc = 4, OUTc = 6;
constexpr int QS = 1536;   // fused qkv weight col count

typedef __attribute__((ext_vector_type(8))) short  bf16x8;
typedef __attribute__((ext_vector_type(4))) float  f32x4;

__device__ __forceinline__ void ld4(float d[4], const float* s) {
    float4 t = *(const float4*)s;
    d[0] = t.x; d[1] = t.y; d[2] = t.z; d[3] = t.w;
}
__device__ __forceinline__ float bf2f(unsigned short u) {
    union { uint32_t i; float f; } c; c.i = ((uint32_t)u) << 16; return c.f;
}
__device__ __forceinline__ unsigned short f2bf(float f) {
    union { float f; uint32_t i; } c; c.f = f;
    uint32_t r = c.i + 0x7FFF + ((c.i >> 16) & 1);
    return (unsigned short)(r >> 16);
}

#define GLDS16(gp, lp) __builtin_amdgcn_global_load_lds(                      \
    (const __attribute__((address_space(1))) uint32_t*)(gp),                  \
    (__attribute__((address_space(3))) uint32_t*)(lp), 16, 0, 0)

// ---------------- all weight transposes+casts in ONE dispatch ------------
// out[n][k] = bf16(in[k][n]) per 64x64 tile.
__global__ __launch_bounds__(256) void castAll(
    const float* __restrict__ Wq, const float* __restrict__ Wk,
    const float* __restrict__ Wv, const float* __restrict__ Wo,
    const float* __restrict__ W1, const float* __restrict__ W2,
    unsigned short* __restrict__ qkvT, unsigned short* __restrict__ WoT,
    unsigned short* __restrict__ W1T, unsigned short* __restrict__ W2T)
{
    const int t = blockIdx.x;
    const float* in; unsigned short* out; int K, N, k0, n0;
    if (t < 1024) {            // qkvo: 16 mats x 8x8 tiles of 512x512
        const int mat = t >> 6, l = mat >> 2, w = mat & 3;
        K = 512; N = 512;
        k0 = ((t >> 3) & 7) << 6; n0 = (t & 7) << 6;
        const float* ws4[4] = {Wq, Wk, Wv, Wo};
        in = ws4[w] + (size_t)l * 512 * 512;
        out = (w < 3) ? qkvT + (size_t)l * QS * 512 + (size_t)w * 512 * 512
                      : WoT + (size_t)l * 512 * 512;
    } else if (t < 2048) {     // W1: 4 x (8 k-tiles x 32 n-tiles)
        const int u = t - 1024, l = u >> 8;
        K = 512; N = 2048;
        k0 = ((u >> 5) & 7) << 6; n0 = (u & 31) << 6;
        in = W1 + (size_t)l * 512 * 2048;
        out = W1T + (size_t)l * 2048 * 512;
    } else {                   // W2: 4 x (32 k-tiles x 8 n-tiles)
        const int u = t - 2048, l = u >> 8;
        K = 2048; N = 512;
        k0 = ((u >> 3) & 31) << 6; n0 = (u & 7) << 6;
        in = W2 + (size_t)l * 2048 * 512;
        out = W2T + (size_t)l * 512 * 2048;
    }
    __shared__ float tbuf[64][65];
    const int c = threadIdx.x & 63, r4 = threadIdx.x >> 6;
    #pragma unroll
    for (int it = 0; it < 16; ++it) {
        const int r = (it << 2) + r4;
        tbuf[r][c] = in[(size_t)(k0 + r) * N + n0 + c];
    }
    __syncthreads();
    #pragma unroll
    for (int it = 0; it < 16; ++it) {
        const int r = (it << 2) + r4;
        out[(size_t)(n0 + r) * K + k0 + c] = f2bf(tbuf[c][r]);
    }
}

// ---------------- proj + positional encoding + layernorm ----------------
__global__ __launch_bounds__(256) void proj_pe_ln(
    const float* __restrict__ x, const float* __restrict__ Wproj,
    const float* __restrict__ bproj, const float* __restrict__ gp,
    const float* __restrict__ bp, float* __restrict__ h,
    unsigned short* __restrict__ hbf, float* __restrict__ notpad,
    float* __restrict__ maskadd)
{
    const int wave = threadIdx.x >> 6, lane = threadIdx.x & 63;
    const int tok = (blockIdx.x << 2) + wave;
    const int s = tok & (Sc - 1);
    const float x0 = x[tok * 3 + 0], x1 = x[tok * 3 + 1], x2 = x[tok * 3 + 2];
    if (lane == 0) {
        const bool pad = (fabsf(x0) + fabsf(x1) + fabsf(x2) == 0.0f);
        notpad[tok]  = pad ? 0.0f : 1.0f;
        maskadd[tok] = pad ? -1e30f : 0.0f;
    }
    const float c = -logf(10000.0f) / (float)Dc;
    float v[8];
    float sum = 0.f, sumsq = 0.f;
    #pragma unroll
    for (int g = 0; g < 2; ++g) {
        const int dbase = (g << 8) + (lane << 2);
        #pragma unroll
        for (int j = 0; j < 4; ++j) {
            const int d = dbase + j;
            float val = fmaf(x0, Wproj[d],
                        fmaf(x1, Wproj[Dc + d],
                        fmaf(x2, Wproj[2 * Dc + d], bproj[d])));
            const float arg = (float)s * expf((float)(d & ~1) * c);
            val += (d & 1) ? cosf(arg) : sinf(arg);
            v[(g << 2) + j] = val;
            sum += val; sumsq += val * val;
        }
    }
    #pragma unroll
    for (int m = 1; m < 64; m <<= 1) {
        sum   += __shfl_xor(sum, m, 64);
        sumsq += __shfl_xor(sumsq, m, 64);
    }
    const float mu = sum * (1.0f / Dc);
    const float var = sumsq * (1.0f / Dc) - mu * mu;
    const float rstd = rsqrtf(var + 1e-5f);
    #pragma unroll
    for (int g = 0; g < 2; ++g) {
        const int dbase = (g << 8) + (lane << 2);
        float gg[4], bb[4];
        ld4(gg, gp + dbase); ld4(bb, bp + dbase);
        float4 r;
        r.x = (v[(g<<2)+0] - mu) * rstd * gg[0] + bb[0];
        r.y = (v[(g<<2)+1] - mu) * rstd * gg[1] + bb[1];
        r.z = (v[(g<<2)+2] - mu) * rstd * gg[2] + bb[2];
        r.w = (v[(g<<2)+3] - mu) * rstd * gg[3] + bb[3];
        *(float4*)(h + (size_t)tok * Dc + dbase) = r;
        ushort4 rb;
        rb.x = f2bf(r.x); rb.y = f2bf(r.y); rb.z = f2bf(r.z); rb.w = f2bf(r.w);
        *(ushort4*)(hbf + (size_t)tok * Dc + dbase) = rb;
    }
}

// ---------------- residual add + layernorm (delta is bf16) ---------------
__global__ __launch_bounds__(256) void add_ln(
    const float* __restrict__ hin, const unsigned short* __restrict__ delta,
    const float* __restrict__ g, const float* __restrict__ b,
    float* __restrict__ hout, unsigned short* __restrict__ hbf)
{
    const int wave = threadIdx.x >> 6, lane = threadIdx.x & 63;
    const int tok = (blockIdx.x << 2) + wave;
    const float* hp = hin + (size_t)tok * Dc;
    float v[8];
    float sum = 0.f, sumsq = 0.f;
    #pragma unroll
    for (int gI = 0; gI < 2; ++gI) {
        const int dbase = (gI << 8) + (lane << 2);
        float a[4];
        ld4(a, hp + dbase);
        if (delta) {
            ushort4 d4 = *(const ushort4*)(delta + (size_t)tok * Dc + dbase);
            a[0] += bf2f(d4.x); a[1] += bf2f(d4.y);
            a[2] += bf2f(d4.z); a[3] += bf2f(d4.w);
        }
        #pragma unroll
        for (int j = 0; j < 4; ++j) {
            v[(gI << 2) + j] = a[j];
            sum += a[j]; sumsq += a[j] * a[j];
        }
    }
    #pragma unroll
    for (int m = 1; m < 64; m <<= 1) {
        sum   += __shfl_xor(sum, m, 64);
        sumsq += __shfl_xor(sumsq, m, 64);
    }
    const float mu = sum * (1.0f / Dc);
    const float var = sumsq * (1.0f / Dc) - mu * mu;
    const float rstd = rsqrtf(var + 1e-5f);
    #pragma unroll
    for (int gI = 0; gI < 2; ++gI) {
        const int dbase = (gI << 8) + (lane << 2);
        float gg[4], bb[4];
        ld4(gg, g + dbase); ld4(bb, b + dbase);
        float4 r;
        r.x = (v[(gI<<2)+0] - mu) * rstd * gg[0] + bb[0];
        r.y = (v[(gI<<2)+1] - mu) * rstd * gg[1] + bb[1];
        r.z = (v[(gI<<2)+2] - mu) * rstd * gg[2] + bb[2];
        r.w = (v[(gI<<2)+3] - mu) * rstd * gg[3] + bb[3];
        *(float4*)(hout + (size_t)tok * Dc + dbase) = r;
        if (hbf) {
            ushort4 rb;
            rb.x = f2bf(r.x); rb.y = f2bf(r.y); rb.z = f2bf(r.z); rb.w = f2bf(r.w);
            *(ushort4*)(hbf + (size_t)tok * Dc + dbase) = rb;
        }
    }
}

// ---------------- bf16 MFMA GEMM: C[M,N] = epi(A[M,K] @ Bt[N,K]^T) -------
// 128xNT tile, BK=64, 256 threads. LDS rows are 128 B; the 16B k-blocks are
// XOR-swizzled (slot = kb ^ (row&7)) on the GLOBAL address side of
// global_load_lds so b128 fragment reads stay bank-balanced.
// EPI: 1 = silu + bf16 out, 2 = bf16 out,
//      3 = qkv: n<512 -> q*0.125 bf16 (stride 1024); 512..1023 -> k bf16;
//               n>=1024 -> v transposed via LDS to vT[bh][dh][s]
template<int EPI, int NT>
__global__ __launch_bounds__(256) void gemm_bf16(
    const unsigned short* __restrict__ A, const unsigned short* __restrict__ Bt,
    void* __restrict__ Cv, void* __restrict__ Cv2, int M, int N, int K)
{
    constexpr int JN = NT / 32;
    constexpr int ABsz = 128 * 64 + NT * 64;
    constexpr int TRst = 136;
    constexpr int SMsz = (EPI == 3 && 128 * TRst > ABsz) ? 128 * TRst : ABsz;
    __shared__ unsigned short smem[SMsz];
    unsigned short* As = smem;
    unsigned short* Bs = smem + 128 * 64;
    const int tid = threadIdx.x;
    const int wave = tid >> 6, lane = tid & 63;
    const int m0 = blockIdx.y << 7;
    const int n0 = blockIdx.x * NT;
    const int wm = (wave >> 1) << 6;
    const int wn = (wave & 1) * (NT / 2);
    const int l15 = lane & 15;
    const int lg  = lane >> 4;
    const int grow  = lane >> 3;                  // staging row within 8-group
    const int gcolk = ((lane & 7) ^ grow) << 3;   // swizzled k element offset

    f32x4 acc[4][JN] = {};

    for (int k0 = 0; k0 < K; k0 += 64) {
        __syncthreads();
        #pragma unroll
        for (int t = 0; t < 4; ++t) {
            const int rb = (t << 5) + (wave << 3);
            GLDS16(A + (size_t)(m0 + rb + grow) * K + k0 + gcolk, &As[rb * 64]);
        }
        #pragma unroll
        for (int t = 0; t < NT / 32; ++t) {
            const int rb = (t << 5) + (wave << 3);
            GLDS16(Bt + (size_t)(n0 + rb + grow) * K + k0 + gcolk, &Bs[rb * 64]);
        }
        __syncthreads();
        #pragma unroll
        for (int h = 0; h < 2; ++h) {
            const int sw = (((h << 2) + lg) ^ (l15 & 7)) << 3;
            bf16x8 af[4], bfr[JN];
            #pragma unroll
            for (int i = 0; i < 4; ++i)
                af[i] = *(const bf16x8*)&As[(wm + (i << 4) + l15) * 64 + sw];
            #pragma unroll
            for (int j = 0; j < JN; ++j)
                bfr[j] = *(const bf16x8*)&Bs[(wn + (j << 4) + l15) * 64 + sw];
            #pragma unroll
            for (int i = 0; i < 4; ++i)
                #pragma unroll
                for (int j = 0; j < JN; ++j)
                    acc[i][j] = __builtin_amdgcn_mfma_f32_16x16x32_bf16(
                        af[i], bfr[j], acc[i][j], 0, 0, 0);
        }
    }

    if constexpr (EPI == 3) {
        if (n0 >= 1024) {   // V: transpose via LDS (reuses As/Bs), b128 writes
            __syncthreads();
            unsigned short* Tr = smem;
            #pragma unroll
            for (int i = 0; i < 4; ++i)
                #pragma unroll
                for (int j = 0; j < JN; ++j)
                    #pragma unroll
                    for (int r = 0; r < 4; ++r)
                        Tr[(wn + (j << 4) + l15) * TRst + wm + (i << 4) + (lg << 2) + r]
                            = f2bf(acc[i][j][r]);
            __syncthreads();
            const int bb = m0 >> 10, s0 = m0 & 1023;
            #pragma unroll
            for (int it = 0; it < 8; ++it) {
                const int idx = (it << 8) + tid;
                const int ln = idx >> 4, lmc = (idx & 15) << 3;
                const int gcol = n0 - 1024 + ln;
                const int head = gcol >> 6, dh = gcol & 63;
                *(bf16x8*)((unsigned short*)Cv2 +
                    (size_t)((((bb << 3) + head) << 6) + dh) * 1024 + s0 + lmc) =
                    *(const bf16x8*)&Tr[ln * TRst + lmc];
            }
            return;
        }
    }

    const int crow0 = m0 + wm + (lg << 2);
    const int ccol0 = n0 + wn + l15;
    #pragma unroll
    for (int i = 0; i < 4; ++i)
        #pragma unroll
        for (int j = 0; j < JN; ++j)
            #pragma unroll
            for (int r = 0; r < 4; ++r) {
                const int row = crow0 + (i << 4) + r;
                const int col = ccol0 + (j << 4);
                float v = acc[i][j][r];
                if (EPI == 3) {
                    if (n0 < 512) v *= 0.125f;     // fold 1/sqrt(DH) into q
                    ((unsigned short*)Cv)[(size_t)row * 1024 + col] = f2bf(v);
                } else {
                    if (EPI == 1) v = v / (1.0f + expf(-v));
                    ((unsigned short*)Cv)[(size_t)row * N + col] = f2bf(v);
                }
            }
}

// ---------------- MFMA flash attention, DH=64, 128-query blocks ----------
// block = 256 threads (4 waves); one (b, head, 128-query tile).
// wave w owns q rows {s*64 + w*16 .. +16} for s=0,1. 128-key iterations.
// blockIdx low bits = b so all q-tiles of one (b,h) share an XCD.
__global__ __launch_bounds__(256, 2) void attn_mfma(
    const unsigned short* __restrict__ qk,   // [8192][1024] bf16, q*0.125 | k
    const unsigned short* __restrict__ vT,   // [64 bh][64 dh][1024 s] bf16
    const float* __restrict__ maskadd,       // 0 or -1e30 per token
    unsigned short* __restrict__ o)          // [8192][512] bf16
{
    constexpr int PST = 124;                  // Ps row stride (elements)
    __shared__ unsigned short Ks[2][128][32]; // panel p: dh 32p.., rows=key
    __shared__ unsigned short Vs[4][64][32];  // panel p: keys 32p.., rows=dh
    __shared__ unsigned short Ps[4][32][PST]; // per-wave P rows=q(2 subs), cols=key
    __shared__ float Madd[128];
    const int tid = threadIdx.x;
    const int wave = tid >> 6, lane = tid & 63;
    const int b  = blockIdx.x & 7;
    const int hh = (blockIdx.x >> 3) & 7;
    const int qt = blockIdx.x >> 6;
    const int q0 = qt << 7;
    const int l15 = lane & 15, lg = lane >> 4;
    const int srow = lane >> 2;
    const int scol = (lane & 3) << 3;

    // ---- stage 128 Q rows into Ks; pull A-fragments (2 subs x 2 panels)
    #pragma unroll
    for (int t = 0; t < 2; ++t)
        #pragma unroll
        for (int p = 0; p < 2; ++p)
            GLDS16(qk + (size_t)((b << 10) + q0 + (t << 6) + (wave << 4) + srow) * 1024
                      + (hh << 6) + (p << 5) + scol,
                   &Ks[p][(t << 6) + (wave << 4)][0]);
    __syncthreads();
    bf16x8 qf[2][2];
    #pragma unroll
    for (int s = 0; s < 2; ++s)
        #pragma unroll
        for (int p = 0; p < 2; ++p)
            qf[s][p] = *(const bf16x8*)&Ks[p][(s << 6) + (wave << 4) + l15][lg << 3];

    f32x4 oacc[2][4] = {};
    float l_part[2][4] = {};

    for (int kt = 0; kt < 8; ++kt) {
        const int k0 = kt << 7;
        __syncthreads();
        #pragma unroll
        for (int t = 0; t < 2; ++t)
            #pragma unroll
            for (int p = 0; p < 2; ++p)
                GLDS16(qk + (size_t)((b << 10) + k0 + (t << 6) + (wave << 4) + srow) * 1024
                          + 512 + (hh << 6) + (p << 5) + scol,
                       &Ks[p][(t << 6) + (wave << 4)][0]);
        #pragma unroll
        for (int kp = 0; kp < 4; ++kp)
            GLDS16(vT + (size_t)((((b << 3) + hh) << 6) + (wave << 4) + srow) * 1024
                      + k0 + (kp << 5) + scol,
                   &Vs[kp][wave << 4][0]);
        if (tid < 128) Madd[tid] = maskadd[(b << 10) + k0 + tid];
        __syncthreads();

        // ---- S = Q K^T : (2 x 16 q) x 128 keys per wave
        f32x4 sacc[2][8] = {};
        #pragma unroll
        for (int j = 0; j < 8; ++j) {
            const bf16x8 kf0 = *(const bf16x8*)&Ks[0][(j << 4) + l15][lg << 3];
            const bf16x8 kf1 = *(const bf16x8*)&Ks[1][(j << 4) + l15][lg << 3];
            #pragma unroll
            for (int s = 0; s < 2; ++s) {
                sacc[s][j] = __builtin_amdgcn_mfma_f32_16x16x32_bf16(qf[s][0], kf0, sacc[s][j], 0, 0, 0);
                sacc[s][j] = __builtin_amdgcn_mfma_f32_16x16x32_bf16(qf[s][1], kf1, sacc[s][j], 0, 0, 0);
            }
        }

        // ---- exp (no max-subtraction), accumulate l, stage P
        #pragma unroll
        for (int s = 0; s < 2; ++s)
            #pragma unroll
            for (int j = 0; j < 8; ++j) {
                const float ma = Madd[(j << 4) + l15];
                #pragma unroll
                for (int r = 0; r < 4; ++r) {
                    const float p = __expf(sacc[s][j][r] + ma);
                    l_part[s][r] += p;
                    Ps[wave][(s << 4) + (lg << 2) + r][(j << 4) + l15] = f2bf(p);
                }
            }
        __asm__ volatile("s_waitcnt lgkmcnt(0)" ::: "memory");

        // ---- O += P V
        #pragma unroll
        for (int kp = 0; kp < 4; ++kp) {
            bf16x8 vf[4];
            #pragma unroll
            for (int j = 0; j < 4; ++j)
                vf[j] = *(const bf16x8*)&Vs[kp][(j << 4) + l15][lg << 3];
            #pragma unroll
            for (int s = 0; s < 2; ++s) {
                const bf16x8 pa = *(const bf16x8*)&Ps[wave][(s << 4) + l15][(kp << 5) + (lg << 3)];
                #pragma unroll
                for (int j = 0; j < 4; ++j)
                    oacc[s][j] = __builtin_amdgcn_mfma_f32_16x16x32_bf16(pa, vf[j], oacc[s][j], 0, 0, 0);
            }
        }
    }

    #pragma unroll
    for (int s = 0; s < 2; ++s)
        #pragma unroll
        for (int r = 0; r < 4; ++r) {
            float l = l_part[s][r];
            #pragma unroll
            for (int m = 1; m < 16; m <<= 1) l += __shfl_xor(l, m, 64);
            l_part[s][r] = 1.0f / l;
        }
    #pragma unroll
    for (int s = 0; s < 2; ++s) {
        const int tokr = (b << 10) + q0 + (s << 6) + (wave << 4) + (lg << 2);
        #pragma unroll
        for (int j = 0; j < 4; ++j)
            #pragma unroll
            for (int r = 0; r < 4; ++r)
                o[(size_t)(tokr + r) * 512 + (hh << 6) + (j << 4) + l15] =
                    f2bf(oacc[s][j][r] * l_part[s][r]);
    }
}

// ---------------- masked mean pool ---------------------------------------
__global__ __launch_bounds__(256) void pool_kernel(
    const float* __restrict__ h, const float* __restrict__ notpad,
    float* __restrict__ pooled, float* __restrict__ counts)
{
    const int b = blockIdx.y;
    const int s0 = blockIdx.x << 5;
    const int t = threadIdx.x;
    float a0 = 0.f, a1 = 0.f;
    for (int ss = 0; ss < 32; ++ss) {
        const float w = notpad[(b << 10) + s0 + ss];
        const float* hp = h + (size_t)((b << 10) + s0 + ss) * Dc;
        a0 = fmaf(w, hp[t], a0);
        a1 = fmaf(w, hp[t + 256], a1);
    }
    atomicAdd(&pooled[b * Dc + t], a0);
    atomicAdd(&pooled[b * Dc + t + 256], a1);
    if (t < 32) {
        float w = notpad[(b << 10) + s0 + t];
        #pragma unroll
        for (int m = 1; m < 32; m <<= 1) w += __shfl_xor(w, m, 64);
        if (t == 0) atomicAdd(&counts[b], w);
    }
}

// ---------------- final tiny GEMV ----------------------------------------
__global__ void out_kernel(
    const float* __restrict__ pooled, const float* __restrict__ counts,
    const float* __restrict__ Wout, const float* __restrict__ bout,
    float* __restrict__ out)
{
    const int bo = blockIdx.x;
    const int b = bo / OUTc, oc = bo % OUTc;
    const int lane = threadIdx.x;
    float acc = 0.f;
    for (int d = lane; d < Dc; d += 64)
        acc = fmaf(pooled[b * Dc + d], Wout[(size_t)d * OUTc + oc], acc);
    #pragma unroll
    for (int m = 1; m < 64; m <<= 1) acc += __shfl_xor(acc, m, 64);
    if (lane == 0) out[b * OUTc + oc] = acc / (counts[b] + 1e-8f) + bout[oc];
}

} // namespace

extern "C" void kernel_launch(void* const* d_in, const int* in_sizes, int n_in,
                              void* d_out, int out_size, void* d_ws, size_t ws_size,
                              hipStream_t stream)
{
    (void)in_sizes; (void)n_in; (void)out_size; (void)ws_size;
    const float* x     = (const float*)d_in[0];
    const float* Wproj = (const float*)d_in[1];
    const float* bproj = (const float*)d_in[2];
    const float* gp    = (const float*)d_in[3];
    const float* bp    = (const float*)d_in[4];
    const float* Wq    = (const float*)d_in[5];
    const float* Wk    = (const float*)d_in[6];
    const float* Wv    = (const float*)d_in[7];
    const float* Wo    = (const float*)d_in[8];
    const float* g1    = (const float*)d_in[9];
    const float* b1    = (const float*)d_in[10];
    const float* W1    = (const float*)d_in[11];
    const float* W2    = (const float*)d_in[12];
    const float* g2    = (const float*)d_in[13];
    const float* b2    = (const float*)d_in[14];
    const float* gf    = (const float*)d_in[15];
    const float* bf    = (const float*)d_in[16];
    const float* Wout  = (const float*)d_in[17];
    const float* bout  = (const float*)d_in[18];
    float* out = (float*)d_out;

    const size_t MiB = 1u << 20;
    char* base = (char*)d_ws;
    float*          h       = (float*)(base);                       // 16 MiB
    unsigned short* h_bf    = (unsigned short*)(base + 16 * MiB);   // 8 MiB
    unsigned short* qk_act  = (unsigned short*)(base + 24 * MiB);   // 16 MiB [8192][1024]
    unsigned short* vT      = (unsigned short*)(base + 40 * MiB);   // 8 MiB [64][64][1024]
    unsigned short* ob_bf   = (unsigned short*)(base + 48 * MiB);   // 8 MiB [8192][512]
    unsigned short* bufB_bf = (unsigned short*)(base + 56 * MiB);   // 8 MiB [8192][512]
    unsigned short* ffa_bf  = (unsigned short*)(base + 24 * MiB);   // 32 MiB (aliases qk/vT/ob)
    unsigned short* qkvT    = (unsigned short*)(base + 72 * MiB);   // 6 MiB
    unsigned short* WoT     = (unsigned short*)(base + 78 * MiB);   // 2 MiB
    unsigned short* W1T     = (unsigned short*)(base + 80 * MiB);   // 8 MiB
    unsigned short* W2T     = (unsigned short*)(base + 88 * MiB);   // 8 MiB
    float*          notpad  = (float*)(base + 96 * MiB);            // 32 KiB
    float*          maskadd = notpad + 8192;                        // 32 KiB
    float*          pooled  = maskadd + 8192;
    float*          counts  = pooled + Bc * Dc;

    const int M = Bc * Sc;   // 8192

    castAll<<<3072, 256, 0, stream>>>(Wq, Wk, Wv, Wo, W1, W2, qkvT, WoT, W1T, W2T);
    proj_pe_ln<<<M / 4, 256, 0, stream>>>(x, Wproj, bproj, gp, bp, h, h_bf, notpad, maskadd);

    for (int l = 0; l < Lc; ++l) {
        gemm_bf16<3, 128><<<dim3(QS / 128, M / 128), 256, 0, stream>>>(
            h_bf, qkvT + (size_t)l * QS * 512, qk_act, vT, M, QS, 512);
        attn_mfma<<<Bc * Hc * (Sc / 128), 256, 0, stream>>>(qk_act, vT, maskadd, ob_bf);
        gemm_bf16<2, 64><<<dim3(512 / 64, M / 128), 256, 0, stream>>>(
            ob_bf, WoT + (size_t)l * 512 * 512, bufB_bf, nullptr, M, 512, 512);
        add_ln<<<M / 4, 256, 0, stream>>>(h, bufB_bf, g1 + (size_t)l * Dc, b1 + (size_t)l * Dc, h, h_bf);
        gemm_bf16<1, 128><<<dim3(FFc / 128, M / 128), 256, 0, stream>>>(
            h_bf, W1T + (size_t)l * FFc * 512, ffa_bf, nullptr, M, FFc, 512);
        gemm_bf16<2, 64><<<dim3(512 / 64, M / 128), 256, 0, stream>>>(
            ffa_bf, W2T + (size_t)l * 512 * FFc, bufB_bf, nullptr, M, 512, FFc);
        add_ln<<<M / 4, 256, 0, stream>>>(h, bufB_bf, g2 + (size_t)l * Dc, b2 + (size_t)l * Dc, h, h_bf);
    }
    add_ln<<<M / 4, 256, 0, stream>>>(h, nullptr, gf, bf, h, nullptr);

    hipMemsetAsync(pooled, 0, (size_t)(Bc * Dc + Bc) * sizeof(float), stream);
    pool_kernel<<<dim3(Sc / 32, Bc), 256, 0, stream>>>(h, notpad, pooled, counts);
    out_kernel<<<Bc * OUTc, 64, 0, stream>>>(pooled, counts, Wout, bout, out);
}